// Round 12
// baseline (1458.110 us; speedup 1.0000x reference)
//
#include <hip/hip_runtime.h>
#include <math.h>

#define Vv 32000
#define Dm 216
#define NLAY 11
#define NHh 4
#define HDd 54
#define FFf 864
#define Bb 2
#define Ss 1024
#define Tt (Bb*Ss)
#define EPSf 1e-5f
#define QKVW 648   // 3*Dm
#define KP 224     // K=216 padded to multiple of 32
#define HDP 64     // head dim padded
#define VTSZ (Ss*HDP)

typedef __attribute__((ext_vector_type(8))) short short8;
typedef __attribute__((ext_vector_type(8))) unsigned short ushort8;
typedef __attribute__((ext_vector_type(4))) float f32x4;

__device__ __forceinline__ unsigned short f2bf(float f) {
    unsigned int u = __float_as_uint(f);
    return (unsigned short)((u + 0x7fffu + ((u >> 16) & 1u)) >> 16);
}
__device__ __forceinline__ float bf2f(unsigned short u) {
    return __uint_as_float(((unsigned int)u) << 16);
}

// ================= setup: embed + tables + zero + weight convs (one launch) ========
__device__ void dev_convw(int relb, int nblk, const float* __restrict__ src,
                          unsigned short* __restrict__ dst,
                          int L, int N, int K, int Npad, int Kp, int rstride,
                          long dls, long doff) {
    size_t total = (size_t)L * Npad * Kp;
    for (size_t idx = (size_t)relb * 256 + threadIdx.x; idx < total;
         idx += (size_t)nblk * 256) {
        int k = (int)(idx % Kp);
        size_t rr = idx / Kp;
        int n = (int)(rr % Npad);
        int l = (int)(rr / Npad);
        float v = (n < N && k < K) ? src[((size_t)l * N + n) * K + k] : 0.f;
        dst[(size_t)l * dls + doff + (size_t)n * rstride + k] = f2bf(v);
    }
}

__device__ void dev_convqkv(int relb, int nblk, const float* __restrict__ src,
                            unsigned short* __restrict__ dst) {
    size_t total = (size_t)NLAY * 768 * KP;
    for (size_t idx = (size_t)relb * 256 + threadIdx.x; idx < total;
         idx += (size_t)nblk * 256) {
        int kk2 = (int)(idx % KP);
        size_t rr = idx / KP;
        int nr = (int)(rr % 768);
        int l = (int)(rr / 768);
        float v = 0.f;
        if (nr < 648 && kk2 < 216) {
            int srow;
            float sc = 1.f;
            if (nr < 432) {
                int which = nr >= 216;
                int cih = nr - which * 216;
                int head = cih / 54, dd = cih % 54;
                int j = dd >> 1, odd = dd & 1;
                srow = which * 216 + head * 54 + j + odd * 27;
                if (!which) sc = 0.13608276348795434f; // 54^-0.5 folded into q
            } else srow = nr;
            v = src[((size_t)l * QKVW + srow) * 216 + kk2] * sc;
        }
        dst[idx] = f2bf(v);
    }
}

// head-sliced o-weight: owh[l][h][n 224][k 64] = o_w[l][n][h*54+k] (zero padded)
__device__ void dev_convowh(int relb, int nblk, const float* __restrict__ src,
                            unsigned short* __restrict__ dst) {
    size_t total = (size_t)NLAY * 4 * 224 * 64;
    for (size_t idx = (size_t)relb * 256 + threadIdx.x; idx < total;
         idx += (size_t)nblk * 256) {
        int kk = (int)(idx & 63);
        size_t rr = idx >> 6;
        int n = (int)(rr % 224);
        size_t rh = rr / 224;
        int h = (int)(rh & 3);
        int l = (int)(rh >> 2);
        float v = (n < 216 && kk < 54)
            ? src[((size_t)l * 216 + n) * 216 + h * 54 + kk] : 0.f;
        dst[idx] = f2bf(v);
    }
}

__global__ void k_setup(const int* __restrict__ ids, const float* __restrict__ emb,
                        float* __restrict__ x,
                        float* __restrict__ cost, float* __restrict__ sint,
                        unsigned int* __restrict__ zp, size_t zwords,
                        const float* __restrict__ qkv_w, unsigned short* __restrict__ qkvw,
                        const float* __restrict__ o_w, unsigned short* __restrict__ owh,
                        const float* __restrict__ gate_w, const float* __restrict__ up_w,
                        unsigned short* __restrict__ guw,
                        const float* __restrict__ down_w, unsigned short* __restrict__ dww,
                        const float* __restrict__ lm_w, unsigned short* __restrict__ lmw)
{
    const int b = blockIdx.x;
    const int tid = threadIdx.x;
    if (b < 2048) {
        int id = ids[b];
        for (int d = tid; d < Dm; d += 256)
            x[(size_t)b * Dm + d] = emb[(size_t)id * Dm + d];
    } else if (b < 2176) {
        for (int idx = (b - 2048) * 256 + tid; idx < 1024 * 27; idx += 128 * 256) {
            int s = idx / 27, j = idx % 27;
            float inv = powf(10000.0f, -2.0f * (float)j / 54.0f);
            float f = (float)s * inv;
            cost[s * 27 + j] = cosf(f);
            sint[s * 27 + j] = sinf(f);
        }
    } else if (b < 2432) {
        for (size_t i = (size_t)(b - 2176) * 256 + tid; i < zwords; i += (size_t)256 * 256)
            zp[i] = 0;
    } else if (b < 2944) {
        dev_convqkv(b - 2432, 512, qkv_w, qkvw);
    } else if (b < 3200) {
        dev_convowh(b - 2944, 256, o_w, owh);
    } else if (b < 3712) {
        dev_convw(b - 3200, 512, gate_w, guw, NLAY, FFf, Dm, 896, KP, 2 * KP, 1792L * KP, 0);
    } else if (b < 4224) {
        dev_convw(b - 3712, 512, up_w, guw, NLAY, FFf, Dm, 896, KP, 2 * KP, 1792L * KP, KP);
    } else if (b < 4736) {
        dev_convw(b - 4224, 512, down_w, dww, NLAY, Dm, FFf, 256, 864, 864, 256L * 864, 0);
    } else {
        dev_convw(b - 4736, 1024, lm_w, lmw, 1, Vv, Dm, Vv, KP, KP, (long)Vv * KP, 0);
    }
}

// ================= shared phase helpers (proven rounds 6-11) =================
__device__ __forceinline__ void normpro(const float* __restrict__ x,
                                        const float* __restrict__ lnw, int m0,
                                        float* rsl, float* lnl, int tid) {
    __syncthreads();
    if (tid < 224) lnl[tid] = (tid < 216) ? lnw[tid] : 0.f;
    if (tid < 128) {
        int row = tid >> 1, half = tid & 1;
        const float* xr = x + (size_t)(m0 + row) * Dm + half * 108;
        float ss = 0.f;
        #pragma unroll
        for (int q = 0; q < 27; ++q) {
            float4 v = *(const float4*)(xr + q * 4);
            ss += v.x * v.x + v.y * v.y + v.z * v.z + v.w * v.w;
        }
        ss += __shfl_xor(ss, 1, 64);
        if (half == 0) rsl[row] = rsqrtf(ss / 216.f + EPSf);
    }
    __syncthreads();
}

__device__ __forceinline__ ushort8 normA(const float* __restrict__ x,
                                         const float* rsl, const float* lnl,
                                         int m0, int row, int base) {
    ushort8 o;
    if (base < 216) {
        const float* pp = x + (size_t)(m0 + row) * Dm + base;
        float r = rsl[row];
        float4 v0 = *(const float4*)pp;
        float4 v1 = *(const float4*)(pp + 4);
        o[0] = f2bf(v0.x * r * lnl[base + 0]);
        o[1] = f2bf(v0.y * r * lnl[base + 1]);
        o[2] = f2bf(v0.z * r * lnl[base + 2]);
        o[3] = f2bf(v0.w * r * lnl[base + 3]);
        o[4] = f2bf(v1.x * r * lnl[base + 4]);
        o[5] = f2bf(v1.y * r * lnl[base + 5]);
        o[6] = f2bf(v1.z * r * lnl[base + 6]);
        o[7] = f2bf(v1.w * r * lnl[base + 7]);
    } else {
        #pragma unroll
        for (int e = 0; e < 8; ++e) o[e] = 0;
    }
    return o;
}

// ================= qkv: 64x64 tiles, norm-fused A, rope/transpose epilogue =========
__global__ __launch_bounds__(256) void k_qkv64(
    const float* __restrict__ x, const unsigned short* __restrict__ W,
    const float* __restrict__ lnw,
    const float* __restrict__ cost, const float* __restrict__ sint,
    unsigned short* __restrict__ Qb, unsigned short* __restrict__ Kb,
    unsigned short* __restrict__ Vt)
{
    __shared__ __align__(16) unsigned char SM[17664];
    unsigned short* lA = (unsigned short*)SM;
    unsigned short* lB = (unsigned short*)(SM + 8192);
    float* rsl = (float*)(SM + 16384);
    float* lnl = (float*)(SM + 16640);
    const int tid = threadIdx.x;
    const int m0 = blockIdx.x * 64;
    const int n0 = blockIdx.y * 64;
    normpro(x, lnw, m0, rsl, lnl, tid);

    const int wid = tid >> 6, lane = tid & 63;
    const int wr = wid >> 1, wc = wid & 1;
    const int r = tid >> 2, kc = tid & 3;
    const int lo = (r >> 4) * 512 + (((kc << 4) | (r & 15)) << 3);

    ushort8 ra = normA(x, rsl, lnl, m0, r, kc * 8);
    ushort8 rb = *(const ushort8*)(W + (size_t)(n0 + r) * KP + kc * 8);
    *(ushort8*)&lA[lo] = ra;
    *(ushort8*)&lB[lo] = rb;
    __syncthreads();

    f32x4 acc[2][2] = {};
    int cur = 0;
    for (int step = 0; step < 7; ++step) {
        const bool more = step < 6;
        if (more) {
            const int k0 = (step + 1) << 5;
            ra = normA(x, rsl, lnl, m0, r, k0 + kc * 8);
            rb = *(const ushort8*)(W + (size_t)(n0 + r) * KP + k0 + kc * 8);
        }
        short8 af[2], bf2[2];
        #pragma unroll
        for (int f = 0; f < 2; ++f) {
            af[f] = *(const short8*)&lA[cur * 2048 + (wr * 2 + f) * 512 + lane * 8];
            bf2[f] = *(const short8*)&lB[cur * 2048 + (wc * 2 + f) * 512 + lane * 8];
        }
        #pragma unroll
        for (int fm = 0; fm < 2; ++fm)
            #pragma unroll
            for (int fn = 0; fn < 2; ++fn)
                acc[fm][fn] = __builtin_amdgcn_mfma_f32_16x16x32_bf16(af[fm], bf2[fn], acc[fm][fn], 0, 0, 0);
        if (more) {
            const int nxt = cur ^ 1;
            *(ushort8*)&lA[nxt * 2048 + lo] = ra;
            *(ushort8*)&lB[nxt * 2048 + lo] = rb;
            __syncthreads();
            cur = nxt;
        }
    }

    const int lc16 = lane & 15, lg = lane >> 4;
    #pragma unroll
    for (int fm = 0; fm < 2; ++fm) {
        const int mrow = m0 + wr * 32 + fm * 16 + lg * 4;
        const int b = mrow >> 10;
        const int st0 = mrow & 1023;
        #pragma unroll
        for (int fn = 0; fn < 2; ++fn) {
            const int ncol = n0 + wc * 32 + fn * 16 + lc16;
            float v0 = acc[fm][fn][0], v1 = acc[fm][fn][1];
            float v2 = acc[fm][fn][2], v3 = acc[fm][fn][3];
            float p0 = __shfl_xor(v0, 1, 64);
            float p1 = __shfl_xor(v1, 1, 64);
            float p2 = __shfl_xor(v2, 1, 64);
            float p3 = __shfl_xor(v3, 1, 64);
            if (ncol < 432) {
                int which = ncol >= 216;
                int cih = ncol - which * 216;
                int head = cih / 54, dd = cih % 54;
                int j = dd >> 1;
                bool odd = dd & 1;
                unsigned short* dst = (which ? Kb : Qb) +
                    ((size_t)(b * NHh + head) * Ss + st0) * HDP + dd;
                float vv[4] = {v0, v1, v2, v3};
                float pp[4] = {p0, p1, p2, p3};
                #pragma unroll
                for (int i = 0; i < 4; ++i) {
                    float c = cost[(st0 + i) * 27 + j];
                    float sn = sint[(st0 + i) * 27 + j];
                    float o = odd ? (vv[i] * c + pp[i] * sn) : (vv[i] * c - pp[i] * sn);
                    dst[(size_t)i * HDP] = f2bf(o);
                }
            } else if (ncol < 648) {
                int d = ncol - 432;
                int head = d / 54, dd = d % 54;
                ushort4 pk;
                pk.x = f2bf(v0); pk.y = f2bf(v1); pk.z = f2bf(v2); pk.w = f2bf(v3);
                *(ushort4*)(Vt + (size_t)(b * NHh + head) * VTSZ + (size_t)dd * Ss + st0) = pk;
            }
        }
    }
}

// ===== fused FFN: rmsnorm + gate/up GEMM + SiLU + down GEMM, 16 rows per block =====
// grid 128 blocks x 256 threads. A (16x224) and act (16x864) staged in frag-order
// LDS; B-fragments for both GEMMs loaded directly from global (L2-resident weights,
// proven o-proj pattern). Down epilogue: non-atomic x += (block owns its 16 rows).
__global__ __launch_bounds__(256) void k_ffn16(
    const float* __restrict__ x_in, float* __restrict__ x,
    const unsigned short* __restrict__ guw_l, const unsigned short* __restrict__ dww_l,
    const float* __restrict__ lnw)
{
    __shared__ __align__(16) unsigned char SM[35776];
    unsigned short* Al  = (unsigned short*)SM;            // 16 rows x 224 k frag-order
    unsigned short* Act = (unsigned short*)(SM + 7168);   // 16 rows x 864 k frag-order
    float* rsl = (float*)(SM + 34816);                    // 16 floats
    float* lnl = (float*)(SM + 34880);                    // 224 floats
    const int tid = threadIdx.x;
    const int m0 = blockIdx.x * 16;
    const int w = tid >> 6, lane = tid & 63;
    const int lc = lane & 15, lg = lane >> 4;

    // 16-row rmsnorm prologue
    if (tid < 224) lnl[tid] = (tid < 216) ? lnw[tid] : 0.f;
    if (tid < 32) {
        int row = tid >> 1, half = tid & 1;
        const float* xr = x_in + (size_t)(m0 + row) * Dm + half * 108;
        float ss = 0.f;
        #pragma unroll
        for (int q = 0; q < 27; ++q) {
            float4 v = *(const float4*)(xr + q * 4);
            ss += v.x * v.x + v.y * v.y + v.z * v.z + v.w * v.w;
        }
        ss += __shfl_xor(ss, 1, 64);
        if (half == 0) rsl[row] = rsqrtf(ss / 216.f + EPSf);
    }
    __syncthreads();

    // stage normalized A: 448 chunks of 8 (row = c/28, kc8 = c%28)
    {
        int c = tid;
        int row = c / 28, kc8 = c % 28;
        *(ushort8*)&Al[(kc8 * 16 + row) * 8] = normA(x_in, rsl, lnl, m0, row, kc8 * 8);
        int c2 = tid + 256;
        if (c2 < 448) {
            int row2 = c2 / 28, k2 = c2 % 28;
            *(ushort8*)&Al[(k2 * 16 + row2) * 8] = normA(x_in, rsl, lnl, m0, row2, k2 * 8);
        }
    }
    __syncthreads();

    // gate/up: each wave owns interleaved cols [w*432, w*432+432) = 27 frags; K=224
    for (int g = 0; g < 27; ++g) {
        const int ncol0 = w * 432 + g * 16;
        f32x4 acc = {};
        #pragma unroll
        for (int ks = 0; ks < 7; ++ks) {
            short8 afr = *(const short8*)&Al[((ks * 4 + lg) * 16 + lc) * 8];
            short8 bfr = *(const short8*)(guw_l + (size_t)(ncol0 + lc) * KP + ks * 32 + lg * 8);
            acc = __builtin_amdgcn_mfma_f32_16x16x32_bf16(afr, bfr, acc, 0, 0, 0);
        }
        // silu(gate)*up -> Act (even interleaved lanes write col ncol>>1)
        #pragma unroll
        for (int i = 0; i < 4; ++i) {
            float v = acc[i];
            float p = __shfl_xor(v, 1, 64);
            if ((lc & 1) == 0) {
                int c = (ncol0 + lc) >> 1;   // 0..863, wave-disjoint ranges
                int row = lg * 4 + i;
                float y = v / (1.f + __expf(-v)) * p;
                Act[((c >> 3) * 16 + row) * 8 + (c & 7)] = f2bf(y);
            }
        }
    }
    __syncthreads();

    // down: M=16, N=224(216), K=864 (27 ksteps); wave w owns n-frags g%4==w
    f32x4 oacc[4] = {};
    for (int ks = 0; ks < 27; ++ks) {
        short8 afr = *(const short8*)&Act[((ks * 4 + lg) * 16 + lc) * 8];
        #pragma unroll
        for (int gi = 0; gi < 4; ++gi) {
            int g = gi * 4 + w;
            if (g < 14) {
                short8 bfr = *(const short8*)(dww_l + (size_t)(g * 16 + lc) * 864 + ks * 32 + lg * 8);
                oacc[gi] = __builtin_amdgcn_mfma_f32_16x16x32_bf16(afr, bfr, oacc[gi], 0, 0, 0);
            }
        }
    }
    #pragma unroll
    for (int gi = 0; gi < 4; ++gi) {
        int g = gi * 4 + w;
        if (g < 14) {
            int col = g * 16 + lc;
            if (col < 216) {
                #pragma unroll
                for (int i = 0; i < 4; ++i) {
                    size_t oi = (size_t)(m0 + lg * 4 + i) * Dm + col;
                    x[oi] += oacc[gi][i];
                }
            }
        }
    }
}

// ===== attention (16 q-rows, 4-wave kv-split, wave-private staging) + fused o-proj =
__global__ __launch_bounds__(256) void k_attn_o16(
    const unsigned short* __restrict__ Qb, const unsigned short* __restrict__ Kb,
    const unsigned short* __restrict__ Vt, const unsigned short* __restrict__ owh_l,
    float* __restrict__ x)
{
    __shared__ __align__(16) unsigned char SM[38912];
    const int tid = threadIdx.x;
    const int qu = blockIdx.x, h = blockIdx.y, b = blockIdx.z;
    const int bh = b * NHh + h;
    const int q0w = qu * 16;
    const int w = tid >> 6, lane = tid & 63;
    const int lc = lane & 15, lg = lane >> 4;

    unsigned short* Klw = (unsigned short*)(SM + w * 4096);          // 32k x 64d frag-order
    unsigned short* Vlw = (unsigned short*)(SM + 16384 + w * 4096);  // 64d x 32k frag-order
    unsigned short* Plw = (unsigned short*)(SM + 32768 + w * 1024);  // 16q x 32k A-frag
    unsigned short* Ol  = (unsigned short*)(SM + 36864);             // 16q x 64k A-frag

    const unsigned short* Qp = Qb + (size_t)bh * VTSZ;
    const unsigned short* Kpp = Kb + (size_t)bh * VTSZ;
    const unsigned short* Vp = Vt + (size_t)bh * VTSZ;
    const unsigned short* owh_h = owh_l + (size_t)h * 224 * 64;

    short8 qa[2];
    #pragma unroll
    for (int half = 0; half < 2; ++half)
        qa[half] = *(const short8*)(Qp + (size_t)(q0w + lc) * HDP + lg * 8 + half * 32);

    f32x4 o4[4] = {};
    float mreg[4] = {-3e38f, -3e38f, -3e38f, -3e38f};
    float lreg[4] = {0.f, 0.f, 0.f, 0.f};

    const int nt = (q0w + 15) / 32 + 1;
    for (int t = w; t < nt; t += 4) {
        const int kv0 = t * 32;
        for (int c = lane; c < 512; c += 64) {
            if (c < 256) {
                int sub = c >> 6;
                int kgrp = sub >> 1, dhalf = sub & 1;
                int dchunk = (c >> 4) & 3, krow = c & 15;
                *(ushort8*)&Klw[sub * 512 + (c & 63) * 8] =
                    *(const ushort8*)(Kpp + (size_t)(kv0 + kgrp * 16 + krow) * HDP + dhalf * 32 + dchunk * 8);
            } else {
                int c2 = c - 256;
                int dgrp = c2 >> 6;
                int kchunk = (c2 >> 4) & 3, dcol = c2 & 15;
                *(ushort8*)&Vlw[dgrp * 512 + (c2 & 63) * 8] =
                    *(const ushort8*)(Vp + (size_t)(dgrp * 16 + dcol) * Ss + kv0 + kchunk * 8);
            }
        }
        f32x4 s4[2] = {};
        #pragma unroll
        for (int dhalf = 0; dhalf < 2; ++dhalf) {
            #pragma unroll
            for (int kgrp = 0; kgrp < 2; ++kgrp) {
                short8 kf = *(const short8*)&Klw[(kgrp * 2 + dhalf) * 512 + lane * 8];
                s4[kgrp] = __builtin_amdgcn_mfma_f32_16x16x32_bf16(qa[dhalf], kf, s4[kgrp], 0, 0, 0);
            }
        }
        if (kv0 + 31 > q0w) {
            #pragma unroll
            for (int kgrp = 0; kgrp < 2; ++kgrp) {
                int kg = kv0 + kgrp * 16 + lc;
                #pragma unroll
                for (int rr = 0; rr < 4; ++rr) {
                    int qg = q0w + lg * 4 + rr;
                    if (kg > qg) s4[kgrp][rr] = -3e38f;
                }
            }
        }
        #pragma unroll
        for (int rr = 0; rr < 4; ++rr) {
            float rm = fmaxf(s4[0][rr], s4[1][rr]);
            #pragma unroll
            for (int msk = 1; msk < 16; msk <<= 1)
                rm = fmaxf(rm, __shfl_xor(rm, msk, 64));
            float mn = fmaxf(mreg[rr], rm);
            float esc = __expf(mreg[rr] - mn);
            mreg[rr] = mn;
            float e0 = __expf(s4[0][rr] - mn);
            float e1 = __expf(s4[1][rr] - mn);
            float rs = e0 + e1;
            #pragma unroll
            for (int msk = 1; msk < 16; msk <<= 1)
                rs += __shfl_xor(rs, msk, 64);
            lreg[rr] = lreg[rr] * esc + rs;
            #pragma unroll
            for (int db = 0; db < 4; ++db) o4[db][rr] *= esc;
            int q = lg * 4 + rr;
            Plw[(((lc >> 3)) * 16 + q) * 8 + (lc & 7)] = f2bf(e0);
            Plw[((2 + (lc >> 3)) * 16 + q) * 8 + (lc & 7)] = f2bf(e1);
        }
        short8 pa = *(const short8*)&Plw[(lg * 16 + lc) * 8];
        #pragma unroll
        for (int db = 0; db < 4; ++db) {
            short8 vf = *(const short8*)&Vlw[db * 512 + lane * 8];
            o4[db] = __builtin_amdgcn_mfma_f32_16x16x32_bf16(pa, vf, o4[db], 0, 0, 0);
        }
    }

    __syncthreads();
    float* mg = (float*)SM;
    const int slot = (w * 64 + lane) * 25;
    #pragma unroll
    for (int rr = 0; rr < 4; ++rr) { mg[slot + rr] = mreg[rr]; mg[slot + 4 + rr] = lreg[rr]; }
    #pragma unroll
    for (int db = 0; db < 4; ++db)
        #pragma unroll
        for (int rr = 0; rr < 4; ++rr) mg[slot + 8 + db * 4 + rr] = o4[db][rr];
    __syncthreads();
    if (w == 0) {
        #pragma unroll
        for (int rr = 0; rr < 4; ++rr) {
            float m = mreg[rr];
            #pragma unroll
            for (int ww = 1; ww < 4; ++ww)
                m = fmaxf(m, mg[(ww * 64 + lane) * 25 + rr]);
            float eself = __expf(mreg[rr] - m);
            float l = lreg[rr] * eself;
            float oc[4];
            #pragma unroll
            for (int db = 0; db < 4; ++db) oc[db] = o4[db][rr] * eself;
            #pragma unroll
            for (int ww = 1; ww < 4; ++ww) {
                int sl = (ww * 64 + lane) * 25;
                float e = __expf(mg[sl + rr] - m);
                l += mg[sl + 4 + rr] * e;
                #pragma unroll
                for (int db = 0; db < 4; ++db) oc[db] += mg[sl + 8 + db * 4 + rr] * e;
            }
            float inv = 1.f / l;
            int q = lg * 4 + rr;
            #pragma unroll
            for (int db = 0; db < 4; ++db) {
                int kchunk = db * 2 + (lc >> 3);
                Ol[(kchunk * 16 + q) * 8 + (lc & 7)] = f2bf(oc[db] * inv);
            }
        }
    }
    __syncthreads();

    f32x4 oacc[4] = {};
    #pragma unroll
    for (int ks = 0; ks < 2; ++ks) {
        short8 afr = *(const short8*)&Ol[ks * 512 + lane * 8];
        #pragma unroll
        for (int gi = 0; gi < 4; ++gi) {
            int g = gi * 4 + w;
            if (g < 14) {
                int n = g * 16 + lc;
                short8 bfr = *(const short8*)(owh_h + (size_t)n * 64 + ks * 32 + lg * 8);
                oacc[gi] = __builtin_amdgcn_mfma_f32_16x16x32_bf16(afr, bfr, oacc[gi], 0, 0, 0);
            }
        }
    }
    #pragma unroll
    for (int gi = 0; gi < 4; ++gi) {
        int g = gi * 4 + w;
        if (g < 14) {
            int col = g * 16 + lc;
            if (col < 216) {
                #pragma unroll
                for (int i = 0; i < 4; ++i) {
                    int row = b * Ss + q0w + lg * 4 + i;
                    atomicAdd(&x[(size_t)row * Dm + col], oacc[gi][i]);
                }
            }
        }
    }
}

// ================= fused MFMA GEMM (128x128) — LM head w/ norm-A ==========
template<int OUTM, bool NORMA>
__global__ __launch_bounds__(256, 2) void k_gemm_f(
    const void* __restrict__ Av, const unsigned short* __restrict__ W,
    const float* __restrict__ res, void* __restrict__ outv,
    const float* __restrict__ lnw, int N, int Kp)
{
    __shared__ __align__(16) unsigned short lds[2][2][4096];
    __shared__ float rsl[128];
    __shared__ float lnl[224];
    const int tid = threadIdx.x;
    const int m0 = blockIdx.x * 128;
    const int n0 = blockIdx.y * 128;
    const int wid = tid >> 6, lane = tid & 63;
    const int wr = wid >> 1, wc = wid & 1;
    const int nsteps = Kp >> 5;

    if constexpr (NORMA) {
        const float* Af = (const float*)Av;
        if (tid < 224) lnl[tid] = (tid < 216) ? lnw[tid] : 0.f;
        int row = tid >> 1, half = tid & 1;
        const float* xr = Af + (size_t)(m0 + row) * 216 + half * 108;
        float ss = 0.f;
        #pragma unroll
        for (int q = 0; q < 27; ++q) {
            float4 v = *(const float4*)(xr + q * 4);
            ss += v.x * v.x + v.y * v.y + v.z * v.z + v.w * v.w;
        }
        ss += __shfl_xor(ss, 1, 64);
        if (half == 0) rsl[row] = rsqrtf(ss / 216.f + EPSf);
        __syncthreads();
    }

    const int i0 = tid, i1 = tid + 256;
    const int rA0 = i0 >> 2, cA0 = i0 & 3;
    const int rA1 = i1 >> 2, cA1 = i1 & 3;
    const int lo0 = (rA0 >> 4) * 512 + (((cA0 << 4) | (rA0 & 15)) << 3);
    const int lo1 = (rA1 >> 4) * 512 + (((cA1 << 4) | (rA1 & 15)) << 3);

    auto loadA = [&](int row, int base) -> ushort8 {
        ushort8 o;
        if constexpr (NORMA) {
            if (base < 216) {
                const float* p = (const float*)Av + (size_t)(m0 + row) * 216 + base;
                float r = rsl[row];
                float4 v0 = *(const float4*)p;
                float4 v1 = *(const float4*)(p + 4);
                o[0] = f2bf(v0.x * r * lnl[base + 0]);
                o[1] = f2bf(v0.y * r * lnl[base + 1]);
                o[2] = f2bf(v0.z * r * lnl[base + 2]);
                o[3] = f2bf(v0.w * r * lnl[base + 3]);
                o[4] = f2bf(v1.x * r * lnl[base + 4]);
                o[5] = f2bf(v1.y * r * lnl[base + 5]);
                o[6] = f2bf(v1.z * r * lnl[base + 6]);
                o[7] = f2bf(v1.w * r * lnl[base + 7]);
            } else {
                #pragma unroll
                for (int e = 0; e < 8; ++e) o[e] = 0;
            }
        } else {
            o = *(const ushort8*)((const unsigned short*)Av + (size_t)(m0 + row) * Kp + base);
        }
        return o;
    };

    ushort8 ra0, ra1, rb0, rb1;
    ra0 = loadA(rA0, cA0 * 8);
    ra1 = loadA(rA1, cA1 * 8);
    rb0 = *(const ushort8*)(W + (size_t)(n0 + rA0) * Kp + cA0 * 8);
    rb1 = *(const ushort8*)(W + (size_t)(n0 + rA1) * Kp + cA1 * 8);
    *(ushort8*)&lds[0][0][lo0] = ra0;
    *(ushort8*)&lds[0][0][lo1] = ra1;
    *(ushort8*)&lds[0][1][lo0] = rb0;
    *(ushort8*)&lds[0][1][lo1] = rb1;
    __syncthreads();

    f32x4 acc[4][4] = {};
    int cur = 0;
    for (int step = 0; step < nsteps; ++step) {
        const bool more = (step + 1) < nsteps;
        if (more) {
            const int k0 = (step + 1) << 5;
            ra0 = loadA(rA0, k0 + cA0 * 8);
            ra1 = loadA(rA1, k0 + cA1 * 8);
            rb0 = *(const ushort8*)(W + (size_t)(n0 + rA0) * Kp + k0 + cA0 * 8);
            rb1 = *(const ushort8*)(W + (size_t)(n0 + rA1) * Kp + k0 + cA1 * 8);
        }
        short8 af[4], bf[4];
        #pragma unroll
        for (int f = 0; f < 4; ++f) {
            af[f] = *(const short8*)&lds[cur][0][(wr * 4 + f) * 512 + lane * 8];
            bf[f] = *(const short8*)&lds[cur][1][(wc * 4 + f) * 512 + lane * 8];
        }
        #pragma unroll
        for (int fm = 0; fm < 4; ++fm)
            #pragma unroll
            for (int fn = 0; fn < 4; ++fn)
                acc[fm][fn] = __builtin_amdgcn_mfma_f32_16x16x32_bf16(af[fm], bf[fn], acc[fm][fn], 0, 0, 0);
        if (more) {
            const int nxt = cur ^ 1;
            *(ushort8*)&lds[nxt][0][lo0] = ra0;
            *(ushort8*)&lds[nxt][0][lo1] = ra1;
            *(ushort8*)&lds[nxt][1][lo0] = rb0;
            *(ushort8*)&lds[nxt][1][lo1] = rb1;
            __syncthreads();
            cur = nxt;
        }
    }

    const int lc16 = lane & 15;
    #pragma unroll
    for (int fm = 0; fm < 4; ++fm) {
        const int mrow = m0 + wr * 64 + fm * 16 + (lane >> 4) * 4;
        #pragma unroll
        for (int fn = 0; fn < 4; ++fn) {
            const int ncol = n0 + wc * 64 + fn * 16 + lc16;
            if (ncol < N) {
                #pragma unroll
                for (int i = 0; i < 4; ++i) {
                    const size_t oi = (size_t)(mrow + i) * N + ncol;
                    float v = acc[fm][fn][i];
                    if (res) v += res[oi];
                    ((float*)outv)[oi] = v;
                }
            }
        }
    }
}

// ================= legacy fp32 fallback kernels =================
__global__ void k_embed(const int* __restrict__ ids, const float* __restrict__ emb,
                        float* __restrict__ x) {
    int t = blockIdx.x;
    int id = ids[t];
    for (int d = threadIdx.x; d < Dm; d += blockDim.x)
        x[(size_t)t * Dm + d] = emb[(size_t)id * Dm + d];
}

__global__ void k_rope_tables(float* __restrict__ cosb, float* __restrict__ sinb) {
    int s = blockIdx.x;
    for (int d = threadIdx.x; d < HDd; d += blockDim.x) {
        int j = d % (HDd / 2);
        float inv = powf(10000.0f, -2.0f * (float)j / (float)HDd);
        float f = (float)s * inv;
        cosb[s * HDd + d] = cosf(f);
        sinb[s * HDd + d] = sinf(f);
    }
}

__global__ void k_rmsnorm(const float* __restrict__ x, const float* __restrict__ w,
                          float* __restrict__ h) {
    int t = blockIdx.x;
    const float* xr = x + (size_t)t * Dm;
    float ss = 0.f;
    for (int d = threadIdx.x; d < Dm; d += 64) { float v = xr[d]; ss += v * v; }
    for (int o = 32; o; o >>= 1) ss += __shfl_down(ss, o, 64);
    float r = __shfl(ss, 0, 64);
    r = rsqrtf(r / (float)Dm + EPSf);
    for (int d = threadIdx.x; d < Dm; d += 64)
        h[(size_t)t * Dm + d] = xr[d] * r * w[d];
}

#define TS 16
__global__ void k_gemm(const float* __restrict__ A, const float* __restrict__ W,
                       const float* __restrict__ res, float* __restrict__ out,
                       int M, int N, int K) {
    __shared__ float As[TS][TS + 1];
    __shared__ float Wsm[TS][TS + 1];
    const int tx = threadIdx.x, ty = threadIdx.y;
    const int m = blockIdx.y * TS + ty;
    const int n = blockIdx.x * TS + tx;
    float acc = 0.f;
    for (int k0 = 0; k0 < K; k0 += TS) {
        int ka = k0 + tx;
        As[ty][tx] = (m < M && ka < K) ? A[(size_t)m * K + ka] : 0.f;
        int nw = blockIdx.x * TS + ty;
        Wsm[ty][tx] = (nw < N && ka < K) ? W[(size_t)nw * K + ka] : 0.f;
        __syncthreads();
        #pragma unroll
        for (int kk = 0; kk < TS; ++kk) acc += As[ty][kk] * Wsm[tx][kk];
        __syncthreads();
    }
    if (m < M && n < N) {
        float r = res ? res[(size_t)m * N + n] : 0.f;
        out[(size_t)m * N + n] = r + acc;
    }
}

__global__ void k_gateup(const float* __restrict__ A, const float* __restrict__ Wg,
                         const float* __restrict__ Wu, float* __restrict__ act,
                         int M, int N, int K) {
    __shared__ float As[TS][TS + 1];
    __shared__ float Gs[TS][TS + 1];
    __shared__ float Us[TS][TS + 1];
    const int tx = threadIdx.x, ty = threadIdx.y;
    const int m = blockIdx.y * TS + ty;
    const int n = blockIdx.x * TS + tx;
    float ag = 0.f, au = 0.f;
    for (int k0 = 0; k0 < K; k0 += TS) {
        int ka = k0 + tx;
        As[ty][tx] = (m < M && ka < K) ? A[(size_t)m * K + ka] : 0.f;
        int nw = blockIdx.x * TS + ty;
        Gs[ty][tx] = (nw < N && ka < K) ? Wg[(size_t)nw * K + ka] : 0.f;
        Us[ty][tx] = (nw < N && ka < K) ? Wu[(size_t)nw * K + ka] : 0.f;
        __syncthreads();
        #pragma unroll
        for (int kk = 0; kk < TS; ++kk) {
            ag += As[ty][kk] * Gs[tx][kk];
            au += As[ty][kk] * Us[tx][kk];
        }
        __syncthreads();
    }
    if (m < M && n < N) {
        float sg = ag / (1.f + expf(-ag));
        act[(size_t)m * N + n] = sg * au;
    }
}

__global__ void k_rope(float* __restrict__ qkv, const float* __restrict__ cosb,
                       const float* __restrict__ sinb) {
    const int t = blockIdx.x;
    const int s = t % Ss;
    float* base = qkv + (size_t)t * QKVW;
    const int HALF = HDd / 2;
    int i = threadIdx.x;
    if (i < 2 * NHh * HALF) {
        int which = i / (NHh * HALF);
        int rem = i % (NHh * HALF);
        int hh = rem / HALF;
        int d = rem % HALF;
        float* ptr = base + which * Dm + hh * HDd;
        float x1 = ptr[d], x2 = ptr[d + HALF];
        float c1 = cosb[s * HDd + d], s1 = sinb[s * HDd + d];
        float c2 = cosb[s * HDd + d + HALF], s2 = sinb[s * HDd + d + HALF];
        ptr[d]        = x1 * c1 - x2 * s1;
        ptr[d + HALF] = x2 * c2 + x1 * s2;
    }
}

__global__ void k_attn(const float* __restrict__ qkv, float* __restrict__ aout) {
    const int q = blockIdx.x, h = blockIdx.y, b = blockIdx.z;
    const int tid = threadIdx.x;
    __shared__ float p[Ss];
    __shared__ float qv[HDd];
    __shared__ float rmax[4], rsum[4];
    const size_t base = (size_t)b * Ss * QKVW;
    const float* qrow = qkv + base + (size_t)q * QKVW + h * HDd;
    if (tid < HDd) qv[tid] = qrow[tid];
    __syncthreads();
    const int nk = q + 1;
    const float scale = 0.13608276348795434f;
    float lmax = -3.0e38f;
    for (int k = tid; k < nk; k += 256) {
        const float* krow = qkv + base + (size_t)k * QKVW + Dm + h * HDd;
        float acc = 0.f;
        #pragma unroll
        for (int d = 0; d < HDd; ++d) acc += qv[d] * krow[d];
        acc *= scale;
        p[k] = acc;
        lmax = fmaxf(lmax, acc);
    }
    for (int o = 32; o; o >>= 1) lmax = fmaxf(lmax, __shfl_down(lmax, o, 64));
    if ((tid & 63) == 0) rmax[tid >> 6] = lmax;
    __syncthreads();
    const float m = fmaxf(fmaxf(rmax[0], rmax[1]), fmaxf(rmax[2], rmax[3]));
    float lsum = 0.f;
    for (int k = tid; k < nk; k += 256) {
        float e = expf(p[k] - m);
        p[k] = e;
        lsum += e;
    }
    for (int o = 32; o; o >>= 1) lsum += __shfl_down(lsum, o, 64);
    if ((tid & 63) == 0) rsum[tid >> 6] = lsum;
    __syncthreads();
    const float inv = 1.f / (rsum[0] + rsum[1] + rsum[2] + rsum[3]);
    for (int d = tid; d < HDd; d += 256) {
        const float* vcol = qkv + base + 2 * Dm + h * HDd + d;
        float acc = 0.f;
        for (int k = 0; k < nk; ++k) acc += p[k] * vcol[(size_t)k * QKVW];
        aout[(size_t)(b * Ss + q) * Dm + h * HDd + d] = acc * inv;
    }
}

// =====================================================================
extern "C" void kernel_launch(void* const* d_in, const int* in_sizes, int n_in,
                              void* d_out, int out_size, void* d_ws, size_t ws_size,
                              hipStream_t stream) {
    const int*   ids    = (const int*)d_in[0];
    const float* emb    = (const float*)d_in[1];
    const float* ln1_w  = (const float*)d_in[2];
    const float* qkv_w  = (const float*)d_in[3];
    const float* o_w    = (const float*)d_in[4];
    const float* ln2_w  = (const float*)d_in[5];
    const float* gate_w = (const float*)d_in[6];
    const float* up_w   = (const float*)d_in[7];
    const float* down_w = (const float*)d_in[8];
    const float* norm_w = (const float*)d_in[9];
    const float* lm_w   = (const float*)d_in[10];
    float* out = (float*)d_out;

    char* base = (char*)d_ws;
    size_t off = 0;
    auto carve = [&](size_t bytes) -> char* {
        char* p = base + off;
        off += (bytes + 255) & ~(size_t)255;
        return p;
    };

    // fp32 buffers
    float* x     = (float*)carve((size_t)Tt * Dm * 4);
    float* cos27 = (float*)carve((size_t)Ss * 27 * 4);
    float* sin27 = (float*)carve((size_t)Ss * 27 * 4);
    // bf16 buffers (Qb..Vt contiguous, pads zeroed every call by setup)
    unsigned short* Qb   = (unsigned short*)carve((size_t)Bb * NHh * VTSZ * 2);
    unsigned short* Kb   = (unsigned short*)carve((size_t)Bb * NHh * VTSZ * 2);
    unsigned short* Vt   = (unsigned short*)carve((size_t)Bb * NHh * VTSZ * 2);
    char* zend = base + off;
    unsigned short* qkvw = (unsigned short*)carve((size_t)NLAY * 768 * KP * 2);
    unsigned short* owh  = (unsigned short*)carve((size_t)NLAY * 4 * 224 * 64 * 2);
    unsigned short* guw  = (unsigned short*)carve((size_t)NLAY * 1792 * KP * 2);
    unsigned short* dww  = (unsigned short*)carve((size_t)NLAY * 256 * 864 * 2);
    unsigned short* lmw  = (unsigned short*)carve((size_t)Vv * KP * 2);
    size_t need = off;

    if (ws_size >= need) {
        size_t zwords = (size_t)(zend - (char*)Qb) / 4;
        k_setup<<<5760, 256, 0, stream>>>(ids, emb, x, cos27, sin27,
            (unsigned int*)Qb, zwords, qkv_w, qkvw, o_w, owh,
            gate_w, up_w, guw, down_w, dww, lm_w, lmw);

        for (int l = 0; l < NLAY; ++l) {
            k_qkv64<<<dim3(32, 12), 256, 0, stream>>>(
                x, qkvw + (size_t)l * 768 * KP, ln1_w + (size_t)l * Dm,
                cos27, sin27, Qb, Kb, Vt);
            k_attn_o16<<<dim3(64, NHh, Bb), 256, 0, stream>>>(
                Qb, Kb, Vt, owh + (size_t)l * 4 * 224 * 64, x);
            k_ffn16<<<128, 256, 0, stream>>>(
                x, x, guw + (size_t)l * 1792 * KP, dww + (size_t)l * 256 * 864,
                ln2_w + (size_t)l * Dm);
        }
        k_gemm_f<0, true><<<dim3(16, 250), 256, 0, stream>>>(
            x, lmw, nullptr, out, norm_w, Vv, KP);
    } else {
        // -------- legacy fp32 fallback --------
        float* ws = (float*)d_ws;
        size_t o2 = 0;
        float* x2    = ws + o2; o2 += (size_t)Tt * Dm;
        float* h2    = ws + o2; o2 += (size_t)Tt * Dm;
        float* qkv2  = ws + o2; o2 += (size_t)Tt * QKVW;
        float* aout2 = ws + o2; o2 += (size_t)Tt * Dm;
        float* act2  = ws + o2; o2 += (size_t)Tt * FFf;
        float* cosb2 = ws + o2; o2 += (size_t)Ss * HDd;
        float* sinb2 = ws + o2; o2 += (size_t)Ss * HDd;

        k_embed<<<Tt, 256, 0, stream>>>(ids, emb, x2);
        k_rope_tables<<<Ss, 64, 0, stream>>>(cosb2, sinb2);
        dim3 blk(TS, TS);
        for (int l = 0; l < NLAY; ++l) {
            k_rmsnorm<<<Tt, 64, 0, stream>>>(x2, ln1_w + (size_t)l * Dm, h2);
            k_gemm<<<dim3((QKVW + TS - 1) / TS, (Tt + TS - 1) / TS), blk, 0, stream>>>(
                h2, qkv_w + (size_t)l * QKVW * Dm, nullptr, qkv2, Tt, QKVW, Dm);
            k_rope<<<Tt, 256, 0, stream>>>(qkv2, cosb2, sinb2);
            k_attn<<<dim3(Ss, NHh, Bb), 256, 0, stream>>>(qkv2, aout2);
            k_gemm<<<dim3((Dm + TS - 1) / TS, (Tt + TS - 1) / TS), blk, 0, stream>>>(
                aout2, o_w + (size_t)l * Dm * Dm, x2, x2, Tt, Dm, Dm);
            k_rmsnorm<<<Tt, 64, 0, stream>>>(x2, ln2_w + (size_t)l * Dm, h2);
            k_gateup<<<dim3((FFf + TS - 1) / TS, (Tt + TS - 1) / TS), blk, 0, stream>>>(
                h2, gate_w + (size_t)l * FFf * Dm, up_w + (size_t)l * FFf * Dm, act2, Tt, FFf, Dm);
            k_gemm<<<dim3((Dm + TS - 1) / TS, (Tt + TS - 1) / TS), blk, 0, stream>>>(
                act2, down_w + (size_t)l * Dm * FFf, x2, x2, Tt, Dm, FFf);
        }
        k_rmsnorm<<<Tt, 64, 0, stream>>>(x2, norm_w, h2);
        k_gemm<<<dim3((Vv + TS - 1) / TS, (Tt + TS - 1) / TS), blk, 0, stream>>>(
            h2, lm_w, nullptr, out, Tt, Vv, Dm);
    }
}

// Round 13
// 906.386 us; speedup vs baseline: 1.6087x; 1.6087x over previous
//
#include <hip/hip_runtime.h>
#include <math.h>

#define Vv 32000
#define Dm 216
#define NLAY 11
#define NHh 4
#define HDd 54
#define FFf 864
#define Bb 2
#define Ss 1024
#define Tt (Bb*Ss)
#define EPSf 1e-5f
#define QKVW 648   // 3*Dm
#define KP 224     // K=216 padded to multiple of 32
#define HDP 64     // head dim padded
#define VTSZ (Ss*HDP)

typedef __attribute__((ext_vector_type(8))) short short8;
typedef __attribute__((ext_vector_type(8))) unsigned short ushort8;
typedef __attribute__((ext_vector_type(4))) float f32x4;

__device__ __forceinline__ unsigned short f2bf(float f) {
    unsigned int u = __float_as_uint(f);
    return (unsigned short)((u + 0x7fffu + ((u >> 16) & 1u)) >> 16);
}
__device__ __forceinline__ float bf2f(unsigned short u) {
    return __uint_as_float(((unsigned int)u) << 16);
}

// ================= setup: embed + tables + zero + weight convs (one launch) ========
__device__ void dev_convw(int relb, int nblk, const float* __restrict__ src,
                          unsigned short* __restrict__ dst,
                          int L, int N, int K, int Npad, int Kp, int rstride,
                          long dls, long doff) {
    size_t total = (size_t)L * Npad * Kp;
    for (size_t idx = (size_t)relb * 256 + threadIdx.x; idx < total;
         idx += (size_t)nblk * 256) {
        int k = (int)(idx % Kp);
        size_t rr = idx / Kp;
        int n = (int)(rr % Npad);
        int l = (int)(rr / Npad);
        float v = (n < N && k < K) ? src[((size_t)l * N + n) * K + k] : 0.f;
        dst[(size_t)l * dls + doff + (size_t)n * rstride + k] = f2bf(v);
    }
}

__device__ void dev_convqkv(int relb, int nblk, const float* __restrict__ src,
                            unsigned short* __restrict__ dst) {
    size_t total = (size_t)NLAY * 768 * KP;
    for (size_t idx = (size_t)relb * 256 + threadIdx.x; idx < total;
         idx += (size_t)nblk * 256) {
        int kk2 = (int)(idx % KP);
        size_t rr = idx / KP;
        int nr = (int)(rr % 768);
        int l = (int)(rr / 768);
        float v = 0.f;
        if (nr < 648 && kk2 < 216) {
            int srow;
            float sc = 1.f;
            if (nr < 432) {
                int which = nr >= 216;
                int cih = nr - which * 216;
                int head = cih / 54, dd = cih % 54;
                int j = dd >> 1, odd = dd & 1;
                srow = which * 216 + head * 54 + j + odd * 27;
                if (!which) sc = 0.13608276348795434f; // 54^-0.5 folded into q
            } else srow = nr;
            v = src[((size_t)l * QKVW + srow) * 216 + kk2] * sc;
        }
        dst[idx] = f2bf(v);
    }
}

// head-sliced o-weight: owh[l][h][n 224][k 64] = o_w[l][n][h*54+k] (zero padded)
__device__ void dev_convowh(int relb, int nblk, const float* __restrict__ src,
                            unsigned short* __restrict__ dst) {
    size_t total = (size_t)NLAY * 4 * 224 * 64;
    for (size_t idx = (size_t)relb * 256 + threadIdx.x; idx < total;
         idx += (size_t)nblk * 256) {
        int kk = (int)(idx & 63);
        size_t rr = idx >> 6;
        int n = (int)(rr % 224);
        size_t rh = rr / 224;
        int h = (int)(rh & 3);
        int l = (int)(rh >> 2);
        float v = (n < 216 && kk < 54)
            ? src[((size_t)l * 216 + n) * 216 + h * 54 + kk] : 0.f;
        dst[idx] = f2bf(v);
    }
}

__global__ void k_setup(const int* __restrict__ ids, const float* __restrict__ emb,
                        float* __restrict__ x,
                        float* __restrict__ cost, float* __restrict__ sint,
                        unsigned int* __restrict__ zp, size_t zwords,
                        const float* __restrict__ qkv_w, unsigned short* __restrict__ qkvw,
                        const float* __restrict__ o_w, unsigned short* __restrict__ owh,
                        const float* __restrict__ gate_w, const float* __restrict__ up_w,
                        unsigned short* __restrict__ guw,
                        const float* __restrict__ down_w, unsigned short* __restrict__ dww,
                        const float* __restrict__ lm_w, unsigned short* __restrict__ lmw)
{
    const int b = blockIdx.x;
    const int tid = threadIdx.x;
    if (b < 2048) {
        int id = ids[b];
        for (int d = tid; d < Dm; d += 256)
            x[(size_t)b * Dm + d] = emb[(size_t)id * Dm + d];
    } else if (b < 2176) {
        for (int idx = (b - 2048) * 256 + tid; idx < 1024 * 27; idx += 128 * 256) {
            int s = idx / 27, j = idx % 27;
            float inv = powf(10000.0f, -2.0f * (float)j / 54.0f);
            float f = (float)s * inv;
            cost[s * 27 + j] = cosf(f);
            sint[s * 27 + j] = sinf(f);
        }
    } else if (b < 2432) {
        for (size_t i = (size_t)(b - 2176) * 256 + tid; i < zwords; i += (size_t)256 * 256)
            zp[i] = 0;
    } else if (b < 2944) {
        dev_convqkv(b - 2432, 512, qkv_w, qkvw);
    } else if (b < 3200) {
        dev_convowh(b - 2944, 256, o_w, owh);
    } else if (b < 3712) {
        dev_convw(b - 3200, 512, gate_w, guw, NLAY, FFf, Dm, 896, KP, 2 * KP, 1792L * KP, 0);
    } else if (b < 4224) {
        dev_convw(b - 3712, 512, up_w, guw, NLAY, FFf, Dm, 896, KP, 2 * KP, 1792L * KP, KP);
    } else if (b < 4736) {
        dev_convw(b - 4224, 512, down_w, dww, NLAY, Dm, FFf, 256, 864, 864, 256L * 864, 0);
    } else {
        dev_convw(b - 4736, 1024, lm_w, lmw, 1, Vv, Dm, Vv, KP, KP, (long)Vv * KP, 0);
    }
}

// ================= shared phase helpers (proven rounds 6-11) =================
__device__ __forceinline__ void normpro(const float* __restrict__ x,
                                        const float* __restrict__ lnw, int m0,
                                        float* rsl, float* lnl, int tid) {
    __syncthreads();
    if (tid < 224) lnl[tid] = (tid < 216) ? lnw[tid] : 0.f;
    if (tid < 128) {
        int row = tid >> 1, half = tid & 1;
        const float* xr = x + (size_t)(m0 + row) * Dm + half * 108;
        float ss = 0.f;
        #pragma unroll
        for (int q = 0; q < 27; ++q) {
            float4 v = *(const float4*)(xr + q * 4);
            ss += v.x * v.x + v.y * v.y + v.z * v.z + v.w * v.w;
        }
        ss += __shfl_xor(ss, 1, 64);
        if (half == 0) rsl[row] = rsqrtf(ss / 216.f + EPSf);
    }
    __syncthreads();
}

__device__ __forceinline__ ushort8 normA(const float* __restrict__ x,
                                         const float* rsl, const float* lnl,
                                         int m0, int row, int base) {
    ushort8 o;
    if (base < 216) {
        const float* pp = x + (size_t)(m0 + row) * Dm + base;
        float r = rsl[row];
        float4 v0 = *(const float4*)pp;
        float4 v1 = *(const float4*)(pp + 4);
        o[0] = f2bf(v0.x * r * lnl[base + 0]);
        o[1] = f2bf(v0.y * r * lnl[base + 1]);
        o[2] = f2bf(v0.z * r * lnl[base + 2]);
        o[3] = f2bf(v0.w * r * lnl[base + 3]);
        o[4] = f2bf(v1.x * r * lnl[base + 4]);
        o[5] = f2bf(v1.y * r * lnl[base + 5]);
        o[6] = f2bf(v1.z * r * lnl[base + 6]);
        o[7] = f2bf(v1.w * r * lnl[base + 7]);
    } else {
        #pragma unroll
        for (int e = 0; e < 8; ++e) o[e] = 0;
    }
    return o;
}

// ================= qkv: 64x64 tiles, norm-fused A, rope/transpose epilogue =========
__global__ __launch_bounds__(256) void k_qkv64(
    const float* __restrict__ x, const unsigned short* __restrict__ W,
    const float* __restrict__ lnw,
    const float* __restrict__ cost, const float* __restrict__ sint,
    unsigned short* __restrict__ Qb, unsigned short* __restrict__ Kb,
    unsigned short* __restrict__ Vt)
{
    __shared__ __align__(16) unsigned char SM[17664];
    unsigned short* lA = (unsigned short*)SM;
    unsigned short* lB = (unsigned short*)(SM + 8192);
    float* rsl = (float*)(SM + 16384);
    float* lnl = (float*)(SM + 16640);
    const int tid = threadIdx.x;
    const int m0 = blockIdx.x * 64;
    const int n0 = blockIdx.y * 64;
    normpro(x, lnw, m0, rsl, lnl, tid);

    const int wid = tid >> 6, lane = tid & 63;
    const int wr = wid >> 1, wc = wid & 1;
    const int r = tid >> 2, kc = tid & 3;
    const int lo = (r >> 4) * 512 + (((kc << 4) | (r & 15)) << 3);

    ushort8 ra = normA(x, rsl, lnl, m0, r, kc * 8);
    ushort8 rb = *(const ushort8*)(W + (size_t)(n0 + r) * KP + kc * 8);
    *(ushort8*)&lA[lo] = ra;
    *(ushort8*)&lB[lo] = rb;
    __syncthreads();

    f32x4 acc[2][2] = {};
    int cur = 0;
    for (int step = 0; step < 7; ++step) {
        const bool more = step < 6;
        if (more) {
            const int k0 = (step + 1) << 5;
            ra = normA(x, rsl, lnl, m0, r, k0 + kc * 8);
            rb = *(const ushort8*)(W + (size_t)(n0 + r) * KP + k0 + kc * 8);
        }
        short8 af[2], bf2[2];
        #pragma unroll
        for (int f = 0; f < 2; ++f) {
            af[f] = *(const short8*)&lA[cur * 2048 + (wr * 2 + f) * 512 + lane * 8];
            bf2[f] = *(const short8*)&lB[cur * 2048 + (wc * 2 + f) * 512 + lane * 8];
        }
        #pragma unroll
        for (int fm = 0; fm < 2; ++fm)
            #pragma unroll
            for (int fn = 0; fn < 2; ++fn)
                acc[fm][fn] = __builtin_amdgcn_mfma_f32_16x16x32_bf16(af[fm], bf2[fn], acc[fm][fn], 0, 0, 0);
        if (more) {
            const int nxt = cur ^ 1;
            *(ushort8*)&lA[nxt * 2048 + lo] = ra;
            *(ushort8*)&lB[nxt * 2048 + lo] = rb;
            __syncthreads();
            cur = nxt;
        }
    }

    const int lc16 = lane & 15, lg = lane >> 4;
    #pragma unroll
    for (int fm = 0; fm < 2; ++fm) {
        const int mrow = m0 + wr * 32 + fm * 16 + lg * 4;
        const int b = mrow >> 10;
        const int st0 = mrow & 1023;
        #pragma unroll
        for (int fn = 0; fn < 2; ++fn) {
            const int ncol = n0 + wc * 32 + fn * 16 + lc16;
            float v0 = acc[fm][fn][0], v1 = acc[fm][fn][1];
            float v2 = acc[fm][fn][2], v3 = acc[fm][fn][3];
            float p0 = __shfl_xor(v0, 1, 64);
            float p1 = __shfl_xor(v1, 1, 64);
            float p2 = __shfl_xor(v2, 1, 64);
            float p3 = __shfl_xor(v3, 1, 64);
            if (ncol < 432) {
                int which = ncol >= 216;
                int cih = ncol - which * 216;
                int head = cih / 54, dd = cih % 54;
                int j = dd >> 1;
                bool odd = dd & 1;
                unsigned short* dst = (which ? Kb : Qb) +
                    ((size_t)(b * NHh + head) * Ss + st0) * HDP + dd;
                float vv[4] = {v0, v1, v2, v3};
                float pp[4] = {p0, p1, p2, p3};
                #pragma unroll
                for (int i = 0; i < 4; ++i) {
                    float c = cost[(st0 + i) * 27 + j];
                    float sn = sint[(st0 + i) * 27 + j];
                    float o = odd ? (vv[i] * c + pp[i] * sn) : (vv[i] * c - pp[i] * sn);
                    dst[(size_t)i * HDP] = f2bf(o);
                }
            } else if (ncol < 648) {
                int d = ncol - 432;
                int head = d / 54, dd = d % 54;
                ushort4 pk;
                pk.x = f2bf(v0); pk.y = f2bf(v1); pk.z = f2bf(v2); pk.w = f2bf(v3);
                *(ushort4*)(Vt + (size_t)(b * NHh + head) * VTSZ + (size_t)dd * Ss + st0) = pk;
            }
        }
    }
}

// ================= gate/up: 64x64 tiles, norm-fused A, silu epilogue =========
__global__ __launch_bounds__(256) void k_gateup64(
    const float* __restrict__ x, const unsigned short* __restrict__ W,
    const float* __restrict__ lnw, unsigned short* __restrict__ act)
{
    __shared__ __align__(16) unsigned char SM[17664];
    unsigned short* lA = (unsigned short*)SM;
    unsigned short* lB = (unsigned short*)(SM + 8192);
    float* rsl = (float*)(SM + 16384);
    float* lnl = (float*)(SM + 16640);
    const int tid = threadIdx.x;
    const int m0 = blockIdx.x * 64;
    const int n0 = blockIdx.y * 64;
    normpro(x, lnw, m0, rsl, lnl, tid);

    const int wid = tid >> 6, lane = tid & 63;
    const int wr = wid >> 1, wc = wid & 1;
    const int r = tid >> 2, kc = tid & 3;
    const int lo = (r >> 4) * 512 + (((kc << 4) | (r & 15)) << 3);

    ushort8 ra = normA(x, rsl, lnl, m0, r, kc * 8);
    ushort8 rb = *(const ushort8*)(W + (size_t)(n0 + r) * KP + kc * 8);
    *(ushort8*)&lA[lo] = ra;
    *(ushort8*)&lB[lo] = rb;
    __syncthreads();

    f32x4 acc[2][2] = {};
    int cur = 0;
    for (int step = 0; step < 7; ++step) {
        const bool more = step < 6;
        if (more) {
            const int k0 = (step + 1) << 5;
            ra = normA(x, rsl, lnl, m0, r, k0 + kc * 8);
            rb = *(const ushort8*)(W + (size_t)(n0 + r) * KP + k0 + kc * 8);
        }
        short8 af[2], bf2[2];
        #pragma unroll
        for (int f = 0; f < 2; ++f) {
            af[f] = *(const short8*)&lA[cur * 2048 + (wr * 2 + f) * 512 + lane * 8];
            bf2[f] = *(const short8*)&lB[cur * 2048 + (wc * 2 + f) * 512 + lane * 8];
        }
        #pragma unroll
        for (int fm = 0; fm < 2; ++fm)
            #pragma unroll
            for (int fn = 0; fn < 2; ++fn)
                acc[fm][fn] = __builtin_amdgcn_mfma_f32_16x16x32_bf16(af[fm], bf2[fn], acc[fm][fn], 0, 0, 0);
        if (more) {
            const int nxt = cur ^ 1;
            *(ushort8*)&lA[nxt * 2048 + lo] = ra;
            *(ushort8*)&lB[nxt * 2048 + lo] = rb;
            __syncthreads();
            cur = nxt;
        }
    }

    const int lc16 = lane & 15, lg = lane >> 4;
    #pragma unroll
    for (int fm = 0; fm < 2; ++fm) {
        const int mrow = m0 + wr * 32 + fm * 16 + lg * 4;
        #pragma unroll
        for (int fn = 0; fn < 2; ++fn) {
            const int ncol = n0 + wc * 32 + fn * 16 + lc16;
            #pragma unroll
            for (int i = 0; i < 4; ++i) {
                float v = acc[fm][fn][i];
                float p = __shfl_xor(v, 1, 64);
                if ((lc16 & 1) == 0 && ncol < 1728) {
                    float y = v / (1.f + __expf(-v)) * p;
                    act[(size_t)(mrow + i) * 864 + (ncol >> 1)] = f2bf(y);
                }
            }
        }
    }
}

// ================= small residual GEMM: 64x64 tile, x += A*W^T =================
__global__ __launch_bounds__(256) void k_gemm_s(
    const unsigned short* __restrict__ A, const unsigned short* __restrict__ W,
    float* __restrict__ xio, int N, int Kp)
{
    __shared__ __align__(16) unsigned short lA[2][2048];
    __shared__ __align__(16) unsigned short lB[2][2048];
    const int tid = threadIdx.x;
    const int m0 = blockIdx.x * 64, n0 = blockIdx.y * 64;
    const int wid = tid >> 6, lane = tid & 63;
    const int wr = wid >> 1, wc = wid & 1;
    const int nsteps = Kp >> 5;
    const int r = tid >> 2, kc = tid & 3;
    const int lo = (r >> 4) * 512 + (((kc << 4) | (r & 15)) << 3);

    ushort8 ra = *(const ushort8*)(A + (size_t)(m0 + r) * Kp + kc * 8);
    ushort8 rb = *(const ushort8*)(W + (size_t)(n0 + r) * Kp + kc * 8);
    *(ushort8*)&lA[0][lo] = ra;
    *(ushort8*)&lB[0][lo] = rb;
    __syncthreads();

    f32x4 acc[2][2] = {};
    int cur = 0;
    for (int step = 0; step < nsteps; ++step) {
        const bool more = (step + 1) < nsteps;
        if (more) {
            const int k0 = (step + 1) << 5;
            ra = *(const ushort8*)(A + (size_t)(m0 + r) * Kp + k0 + kc * 8);
            rb = *(const ushort8*)(W + (size_t)(n0 + r) * Kp + k0 + kc * 8);
        }
        short8 af[2], bf2[2];
        #pragma unroll
        for (int f = 0; f < 2; ++f) {
            af[f] = *(const short8*)&lA[cur][(wr * 2 + f) * 512 + lane * 8];
            bf2[f] = *(const short8*)&lB[cur][(wc * 2 + f) * 512 + lane * 8];
        }
        #pragma unroll
        for (int fm = 0; fm < 2; ++fm)
            #pragma unroll
            for (int fn = 0; fn < 2; ++fn)
                acc[fm][fn] = __builtin_amdgcn_mfma_f32_16x16x32_bf16(af[fm], bf2[fn], acc[fm][fn], 0, 0, 0);
        if (more) {
            const int nxt = cur ^ 1;
            *(ushort8*)&lA[nxt][lo] = ra;
            *(ushort8*)&lB[nxt][lo] = rb;
            __syncthreads();
            cur = nxt;
        }
    }

    #pragma unroll
    for (int fm = 0; fm < 2; ++fm) {
        const int mrow = m0 + wr * 32 + fm * 16 + (lane >> 4) * 4;
        #pragma unroll
        for (int fn = 0; fn < 2; ++fn) {
            const int ncol = n0 + wc * 32 + fn * 16 + (lane & 15);
            if (ncol < N) {
                #pragma unroll
                for (int i = 0; i < 4; ++i) {
                    const size_t oi = (size_t)(mrow + i) * N + ncol;
                    xio[oi] += acc[fm][fn][i];
                }
            }
        }
    }
}

// ===== attention (16 q-rows, 4-wave kv-split, wave-private staging) + fused o-proj =
__global__ __launch_bounds__(256) void k_attn_o16(
    const unsigned short* __restrict__ Qb, const unsigned short* __restrict__ Kb,
    const unsigned short* __restrict__ Vt, const unsigned short* __restrict__ owh_l,
    float* __restrict__ x)
{
    __shared__ __align__(16) unsigned char SM[38912];
    const int tid = threadIdx.x;
    const int qu = blockIdx.x, h = blockIdx.y, b = blockIdx.z;
    const int bh = b * NHh + h;
    const int q0w = qu * 16;
    const int w = tid >> 6, lane = tid & 63;
    const int lc = lane & 15, lg = lane >> 4;

    unsigned short* Klw = (unsigned short*)(SM + w * 4096);          // 32k x 64d frag-order
    unsigned short* Vlw = (unsigned short*)(SM + 16384 + w * 4096);  // 64d x 32k frag-order
    unsigned short* Plw = (unsigned short*)(SM + 32768 + w * 1024);  // 16q x 32k A-frag
    unsigned short* Ol  = (unsigned short*)(SM + 36864);             // 16q x 64k A-frag

    const unsigned short* Qp = Qb + (size_t)bh * VTSZ;
    const unsigned short* Kpp = Kb + (size_t)bh * VTSZ;
    const unsigned short* Vp = Vt + (size_t)bh * VTSZ;
    const unsigned short* owh_h = owh_l + (size_t)h * 224 * 64;

    short8 qa[2];
    #pragma unroll
    for (int half = 0; half < 2; ++half)
        qa[half] = *(const short8*)(Qp + (size_t)(q0w + lc) * HDP + lg * 8 + half * 32);

    f32x4 o4[4] = {};
    float mreg[4] = {-3e38f, -3e38f, -3e38f, -3e38f};
    float lreg[4] = {0.f, 0.f, 0.f, 0.f};

    const int nt = (q0w + 15) / 32 + 1;
    for (int t = w; t < nt; t += 4) {
        const int kv0 = t * 32;
        for (int c = lane; c < 512; c += 64) {
            if (c < 256) {
                int sub = c >> 6;
                int kgrp = sub >> 1, dhalf = sub & 1;
                int dchunk = (c >> 4) & 3, krow = c & 15;
                *(ushort8*)&Klw[sub * 512 + (c & 63) * 8] =
                    *(const ushort8*)(Kpp + (size_t)(kv0 + kgrp * 16 + krow) * HDP + dhalf * 32 + dchunk * 8);
            } else {
                int c2 = c - 256;
                int dgrp = c2 >> 6;
                int kchunk = (c2 >> 4) & 3, dcol = c2 & 15;
                *(ushort8*)&Vlw[dgrp * 512 + (c2 & 63) * 8] =
                    *(const ushort8*)(Vp + (size_t)(dgrp * 16 + dcol) * Ss + kv0 + kchunk * 8);
            }
        }
        f32x4 s4[2] = {};
        #pragma unroll
        for (int dhalf = 0; dhalf < 2; ++dhalf) {
            #pragma unroll
            for (int kgrp = 0; kgrp < 2; ++kgrp) {
                short8 kf = *(const short8*)&Klw[(kgrp * 2 + dhalf) * 512 + lane * 8];
                s4[kgrp] = __builtin_amdgcn_mfma_f32_16x16x32_bf16(qa[dhalf], kf, s4[kgrp], 0, 0, 0);
            }
        }
        if (kv0 + 31 > q0w) {
            #pragma unroll
            for (int kgrp = 0; kgrp < 2; ++kgrp) {
                int kg = kv0 + kgrp * 16 + lc;
                #pragma unroll
                for (int rr = 0; rr < 4; ++rr) {
                    int qg = q0w + lg * 4 + rr;
                    if (kg > qg) s4[kgrp][rr] = -3e38f;
                }
            }
        }
        #pragma unroll
        for (int rr = 0; rr < 4; ++rr) {
            float rm = fmaxf(s4[0][rr], s4[1][rr]);
            #pragma unroll
            for (int msk = 1; msk < 16; msk <<= 1)
                rm = fmaxf(rm, __shfl_xor(rm, msk, 64));
            float mn = fmaxf(mreg[rr], rm);
            float esc = __expf(mreg[rr] - mn);
            mreg[rr] = mn;
            float e0 = __expf(s4[0][rr] - mn);
            float e1 = __expf(s4[1][rr] - mn);
            float rs = e0 + e1;
            #pragma unroll
            for (int msk = 1; msk < 16; msk <<= 1)
                rs += __shfl_xor(rs, msk, 64);
            lreg[rr] = lreg[rr] * esc + rs;
            #pragma unroll
            for (int db = 0; db < 4; ++db) o4[db][rr] *= esc;
            int q = lg * 4 + rr;
            Plw[(((lc >> 3)) * 16 + q) * 8 + (lc & 7)] = f2bf(e0);
            Plw[((2 + (lc >> 3)) * 16 + q) * 8 + (lc & 7)] = f2bf(e1);
        }
        short8 pa = *(const short8*)&Plw[(lg * 16 + lc) * 8];
        #pragma unroll
        for (int db = 0; db < 4; ++db) {
            short8 vf = *(const short8*)&Vlw[db * 512 + lane * 8];
            o4[db] = __builtin_amdgcn_mfma_f32_16x16x32_bf16(pa, vf, o4[db], 0, 0, 0);
        }
    }

    __syncthreads();
    float* mg = (float*)SM;
    const int slot = (w * 64 + lane) * 25;
    #pragma unroll
    for (int rr = 0; rr < 4; ++rr) { mg[slot + rr] = mreg[rr]; mg[slot + 4 + rr] = lreg[rr]; }
    #pragma unroll
    for (int db = 0; db < 4; ++db)
        #pragma unroll
        for (int rr = 0; rr < 4; ++rr) mg[slot + 8 + db * 4 + rr] = o4[db][rr];
    __syncthreads();
    if (w == 0) {
        #pragma unroll
        for (int rr = 0; rr < 4; ++rr) {
            float m = mreg[rr];
            #pragma unroll
            for (int ww = 1; ww < 4; ++ww)
                m = fmaxf(m, mg[(ww * 64 + lane) * 25 + rr]);
            float eself = __expf(mreg[rr] - m);
            float l = lreg[rr] * eself;
            float oc[4];
            #pragma unroll
            for (int db = 0; db < 4; ++db) oc[db] = o4[db][rr] * eself;
            #pragma unroll
            for (int ww = 1; ww < 4; ++ww) {
                int sl = (ww * 64 + lane) * 25;
                float e = __expf(mg[sl + rr] - m);
                l += mg[sl + 4 + rr] * e;
                #pragma unroll
                for (int db = 0; db < 4; ++db) oc[db] += mg[sl + 8 + db * 4 + rr] * e;
            }
            float inv = 1.f / l;
            int q = lg * 4 + rr;
            #pragma unroll
            for (int db = 0; db < 4; ++db) {
                int kchunk = db * 2 + (lc >> 3);
                Ol[(kchunk * 16 + q) * 8 + (lc & 7)] = f2bf(oc[db] * inv);
            }
        }
    }
    __syncthreads();

    f32x4 oacc[4] = {};
    #pragma unroll
    for (int ks = 0; ks < 2; ++ks) {
        short8 afr = *(const short8*)&Ol[ks * 512 + lane * 8];
        #pragma unroll
        for (int gi = 0; gi < 4; ++gi) {
            int g = gi * 4 + w;
            if (g < 14) {
                int n = g * 16 + lc;
                short8 bfr = *(const short8*)(owh_h + (size_t)n * 64 + ks * 32 + lg * 8);
                oacc[gi] = __builtin_amdgcn_mfma_f32_16x16x32_bf16(afr, bfr, oacc[gi], 0, 0, 0);
            }
        }
    }
    #pragma unroll
    for (int gi = 0; gi < 4; ++gi) {
        int g = gi * 4 + w;
        if (g < 14) {
            int col = g * 16 + lc;
            if (col < 216) {
                #pragma unroll
                for (int i = 0; i < 4; ++i) {
                    int row = b * Ss + q0w + lg * 4 + i;
                    atomicAdd(&x[(size_t)row * Dm + col], oacc[gi][i]);
                }
            }
        }
    }
}

// ================= fused MFMA GEMM (128x128) — LM head w/ norm-A ==========
template<int OUTM, bool NORMA>
__global__ __launch_bounds__(256, 2) void k_gemm_f(
    const void* __restrict__ Av, const unsigned short* __restrict__ W,
    const float* __restrict__ res, void* __restrict__ outv,
    const float* __restrict__ lnw, int N, int Kp)
{
    __shared__ __align__(16) unsigned short lds[2][2][4096];
    __shared__ float rsl[128];
    __shared__ float lnl[224];
    const int tid = threadIdx.x;
    const int m0 = blockIdx.x * 128;
    const int n0 = blockIdx.y * 128;
    const int wid = tid >> 6, lane = tid & 63;
    const int wr = wid >> 1, wc = wid & 1;
    const int nsteps = Kp >> 5;

    if constexpr (NORMA) {
        const float* Af = (const float*)Av;
        if (tid < 224) lnl[tid] = (tid < 216) ? lnw[tid] : 0.f;
        int row = tid >> 1, half = tid & 1;
        const float* xr = Af + (size_t)(m0 + row) * 216 + half * 108;
        float ss = 0.f;
        #pragma unroll
        for (int q = 0; q < 27; ++q) {
            float4 v = *(const float4*)(xr + q * 4);
            ss += v.x * v.x + v.y * v.y + v.z * v.z + v.w * v.w;
        }
        ss += __shfl_xor(ss, 1, 64);
        if (half == 0) rsl[row] = rsqrtf(ss / 216.f + EPSf);
        __syncthreads();
    }

    const int i0 = tid, i1 = tid + 256;
    const int rA0 = i0 >> 2, cA0 = i0 & 3;
    const int rA1 = i1 >> 2, cA1 = i1 & 3;
    const int lo0 = (rA0 >> 4) * 512 + (((cA0 << 4) | (rA0 & 15)) << 3);
    const int lo1 = (rA1 >> 4) * 512 + (((cA1 << 4) | (rA1 & 15)) << 3);

    auto loadA = [&](int row, int base) -> ushort8 {
        ushort8 o;
        if constexpr (NORMA) {
            if (base < 216) {
                const float* p = (const float*)Av + (size_t)(m0 + row) * 216 + base;
                float r = rsl[row];
                float4 v0 = *(const float4*)p;
                float4 v1 = *(const float4*)(p + 4);
                o[0] = f2bf(v0.x * r * lnl[base + 0]);
                o[1] = f2bf(v0.y * r * lnl[base + 1]);
                o[2] = f2bf(v0.z * r * lnl[base + 2]);
                o[3] = f2bf(v0.w * r * lnl[base + 3]);
                o[4] = f2bf(v1.x * r * lnl[base + 4]);
                o[5] = f2bf(v1.y * r * lnl[base + 5]);
                o[6] = f2bf(v1.z * r * lnl[base + 6]);
                o[7] = f2bf(v1.w * r * lnl[base + 7]);
            } else {
                #pragma unroll
                for (int e = 0; e < 8; ++e) o[e] = 0;
            }
        } else {
            o = *(const ushort8*)((const unsigned short*)Av + (size_t)(m0 + row) * Kp + base);
        }
        return o;
    };

    ushort8 ra0, ra1, rb0, rb1;
    ra0 = loadA(rA0, cA0 * 8);
    ra1 = loadA(rA1, cA1 * 8);
    rb0 = *(const ushort8*)(W + (size_t)(n0 + rA0) * Kp + cA0 * 8);
    rb1 = *(const ushort8*)(W + (size_t)(n0 + rA1) * Kp + cA1 * 8);
    *(ushort8*)&lds[0][0][lo0] = ra0;
    *(ushort8*)&lds[0][0][lo1] = ra1;
    *(ushort8*)&lds[0][1][lo0] = rb0;
    *(ushort8*)&lds[0][1][lo1] = rb1;
    __syncthreads();

    f32x4 acc[4][4] = {};
    int cur = 0;
    for (int step = 0; step < nsteps; ++step) {
        const bool more = (step + 1) < nsteps;
        if (more) {
            const int k0 = (step + 1) << 5;
            ra0 = loadA(rA0, k0 + cA0 * 8);
            ra1 = loadA(rA1, k0 + cA1 * 8);
            rb0 = *(const ushort8*)(W + (size_t)(n0 + rA0) * Kp + k0 + cA0 * 8);
            rb1 = *(const ushort8*)(W + (size_t)(n0 + rA1) * Kp + k0 + cA1 * 8);
        }
        short8 af[4], bf[4];
        #pragma unroll
        for (int f = 0; f < 4; ++f) {
            af[f] = *(const short8*)&lds[cur][0][(wr * 4 + f) * 512 + lane * 8];
            bf[f] = *(const short8*)&lds[cur][1][(wc * 4 + f) * 512 + lane * 8];
        }
        #pragma unroll
        for (int fm = 0; fm < 4; ++fm)
            #pragma unroll
            for (int fn = 0; fn < 4; ++fn)
                acc[fm][fn] = __builtin_amdgcn_mfma_f32_16x16x32_bf16(af[fm], bf[fn], acc[fm][fn], 0, 0, 0);
        if (more) {
            const int nxt = cur ^ 1;
            *(ushort8*)&lds[nxt][0][lo0] = ra0;
            *(ushort8*)&lds[nxt][0][lo1] = ra1;
            *(ushort8*)&lds[nxt][1][lo0] = rb0;
            *(ushort8*)&lds[nxt][1][lo1] = rb1;
            __syncthreads();
            cur = nxt;
        }
    }

    const int lc16 = lane & 15;
    #pragma unroll
    for (int fm = 0; fm < 4; ++fm) {
        const int mrow = m0 + wr * 64 + fm * 16 + (lane >> 4) * 4;
        #pragma unroll
        for (int fn = 0; fn < 4; ++fn) {
            const int ncol = n0 + wc * 64 + fn * 16 + lc16;
            if (ncol < N) {
                #pragma unroll
                for (int i = 0; i < 4; ++i) {
                    const size_t oi = (size_t)(mrow + i) * N + ncol;
                    float v = acc[fm][fn][i];
                    if (res) v += res[oi];
                    ((float*)outv)[oi] = v;
                }
            }
        }
    }
}

// ================= legacy fp32 fallback kernels =================
__global__ void k_embed(const int* __restrict__ ids, const float* __restrict__ emb,
                        float* __restrict__ x) {
    int t = blockIdx.x;
    int id = ids[t];
    for (int d = threadIdx.x; d < Dm; d += blockDim.x)
        x[(size_t)t * Dm + d] = emb[(size_t)id * Dm + d];
}

__global__ void k_rope_tables(float* __restrict__ cosb, float* __restrict__ sinb) {
    int s = blockIdx.x;
    for (int d = threadIdx.x; d < HDd; d += blockDim.x) {
        int j = d % (HDd / 2);
        float inv = powf(10000.0f, -2.0f * (float)j / (float)HDd);
        float f = (float)s * inv;
        cosb[s * HDd + d] = cosf(f);
        sinb[s * HDd + d] = sinf(f);
    }
}

__global__ void k_rmsnorm(const float* __restrict__ x, const float* __restrict__ w,
                          float* __restrict__ h) {
    int t = blockIdx.x;
    const float* xr = x + (size_t)t * Dm;
    float ss = 0.f;
    for (int d = threadIdx.x; d < Dm; d += 64) { float v = xr[d]; ss += v * v; }
    for (int o = 32; o; o >>= 1) ss += __shfl_down(ss, o, 64);
    float r = __shfl(ss, 0, 64);
    r = rsqrtf(r / (float)Dm + EPSf);
    for (int d = threadIdx.x; d < Dm; d += 64)
        h[(size_t)t * Dm + d] = xr[d] * r * w[d];
}

#define TS 16
__global__ void k_gemm(const float* __restrict__ A, const float* __restrict__ W,
                       const float* __restrict__ res, float* __restrict__ out,
                       int M, int N, int K) {
    __shared__ float As[TS][TS + 1];
    __shared__ float Wsm[TS][TS + 1];
    const int tx = threadIdx.x, ty = threadIdx.y;
    const int m = blockIdx.y * TS + ty;
    const int n = blockIdx.x * TS + tx;
    float acc = 0.f;
    for (int k0 = 0; k0 < K; k0 += TS) {
        int ka = k0 + tx;
        As[ty][tx] = (m < M && ka < K) ? A[(size_t)m * K + ka] : 0.f;
        int nw = blockIdx.x * TS + ty;
        Wsm[ty][tx] = (nw < N && ka < K) ? W[(size_t)nw * K + ka] : 0.f;
        __syncthreads();
        #pragma unroll
        for (int kk = 0; kk < TS; ++kk) acc += As[ty][kk] * Wsm[tx][kk];
        __syncthreads();
    }
    if (m < M && n < N) {
        float r = res ? res[(size_t)m * N + n] : 0.f;
        out[(size_t)m * N + n] = r + acc;
    }
}

__global__ void k_gateup(const float* __restrict__ A, const float* __restrict__ Wg,
                         const float* __restrict__ Wu, float* __restrict__ act,
                         int M, int N, int K) {
    __shared__ float As[TS][TS + 1];
    __shared__ float Gs[TS][TS + 1];
    __shared__ float Us[TS][TS + 1];
    const int tx = threadIdx.x, ty = threadIdx.y;
    const int m = blockIdx.y * TS + ty;
    const int n = blockIdx.x * TS + tx;
    float ag = 0.f, au = 0.f;
    for (int k0 = 0; k0 < K; k0 += TS) {
        int ka = k0 + tx;
        As[ty][tx] = (m < M && ka < K) ? A[(size_t)m * K + ka] : 0.f;
        int nw = blockIdx.x * TS + ty;
        Gs[ty][tx] = (nw < N && ka < K) ? Wg[(size_t)nw * K + ka] : 0.f;
        Us[ty][tx] = (nw < N && ka < K) ? Wu[(size_t)nw * K + ka] : 0.f;
        __syncthreads();
        #pragma unroll
        for (int kk = 0; kk < TS; ++kk) {
            ag += As[ty][kk] * Gs[tx][kk];
            au += As[ty][kk] * Us[tx][kk];
        }
        __syncthreads();
    }
    if (m < M && n < N) {
        float sg = ag / (1.f + expf(-ag));
        act[(size_t)m * N + n] = sg * au;
    }
}

__global__ void k_rope(float* __restrict__ qkv, const float* __restrict__ cosb,
                       const float* __restrict__ sinb) {
    const int t = blockIdx.x;
    const int s = t % Ss;
    float* base = qkv + (size_t)t * QKVW;
    const int HALF = HDd / 2;
    int i = threadIdx.x;
    if (i < 2 * NHh * HALF) {
        int which = i / (NHh * HALF);
        int rem = i % (NHh * HALF);
        int hh = rem / HALF;
        int d = rem % HALF;
        float* ptr = base + which * Dm + hh * HDd;
        float x1 = ptr[d], x2 = ptr[d + HALF];
        float c1 = cosb[s * HDd + d], s1 = sinb[s * HDd + d];
        float c2 = cosb[s * HDd + d + HALF], s2 = sinb[s * HDd + d + HALF];
        ptr[d]        = x1 * c1 - x2 * s1;
        ptr[d + HALF] = x2 * c2 + x1 * s2;
    }
}

__global__ void k_attn(const float* __restrict__ qkv, float* __restrict__ aout) {
    const int q = blockIdx.x, h = blockIdx.y, b = blockIdx.z;
    const int tid = threadIdx.x;
    __shared__ float p[Ss];
    __shared__ float qv[HDd];
    __shared__ float rmax[4], rsum[4];
    const size_t base = (size_t)b * Ss * QKVW;
    const float* qrow = qkv + base + (size_t)q * QKVW + h * HDd;
    if (tid < HDd) qv[tid] = qrow[tid];
    __syncthreads();
    const int nk = q + 1;
    const float scale = 0.13608276348795434f;
    float lmax = -3.0e38f;
    for (int k = tid; k < nk; k += 256) {
        const float* krow = qkv + base + (size_t)k * QKVW + Dm + h * HDd;
        float acc = 0.f;
        #pragma unroll
        for (int d = 0; d < HDd; ++d) acc += qv[d] * krow[d];
        acc *= scale;
        p[k] = acc;
        lmax = fmaxf(lmax, acc);
    }
    for (int o = 32; o; o >>= 1) lmax = fmaxf(lmax, __shfl_down(lmax, o, 64));
    if ((tid & 63) == 0) rmax[tid >> 6] = lmax;
    __syncthreads();
    const float m = fmaxf(fmaxf(rmax[0], rmax[1]), fmaxf(rmax[2], rmax[3]));
    float lsum = 0.f;
    for (int k = tid; k < nk; k += 256) {
        float e = expf(p[k] - m);
        p[k] = e;
        lsum += e;
    }
    for (int o = 32; o; o >>= 1) lsum += __shfl_down(lsum, o, 64);
    if ((tid & 63) == 0) rsum[tid >> 6] = lsum;
    __syncthreads();
    const float inv = 1.f / (rsum[0] + rsum[1] + rsum[2] + rsum[3]);
    for (int d = tid; d < HDd; d += 256) {
        const float* vcol = qkv + base + 2 * Dm + h * HDd + d;
        float acc = 0.f;
        for (int k = 0; k < nk; ++k) acc += p[k] * vcol[(size_t)k * QKVW];
        aout[(size_t)(b * Ss + q) * Dm + h * HDd + d] = acc * inv;
    }
}

// =====================================================================
extern "C" void kernel_launch(void* const* d_in, const int* in_sizes, int n_in,
                              void* d_out, int out_size, void* d_ws, size_t ws_size,
                              hipStream_t stream) {
    const int*   ids    = (const int*)d_in[0];
    const float* emb    = (const float*)d_in[1];
    const float* ln1_w  = (const float*)d_in[2];
    const float* qkv_w  = (const float*)d_in[3];
    const float* o_w    = (const float*)d_in[4];
    const float* ln2_w  = (const float*)d_in[5];
    const float* gate_w = (const float*)d_in[6];
    const float* up_w   = (const float*)d_in[7];
    const float* down_w = (const float*)d_in[8];
    const float* norm_w = (const float*)d_in[9];
    const float* lm_w   = (const float*)d_in[10];
    float* out = (float*)d_out;

    char* base = (char*)d_ws;
    size_t off = 0;
    auto carve = [&](size_t bytes) -> char* {
        char* p = base + off;
        off += (bytes + 255) & ~(size_t)255;
        return p;
    };

    // fp32 buffers
    float* x     = (float*)carve((size_t)Tt * Dm * 4);
    float* cos27 = (float*)carve((size_t)Ss * 27 * 4);
    float* sin27 = (float*)carve((size_t)Ss * 27 * 4);
    // bf16 buffers (Qb..Vt contiguous, pads zeroed every call by setup)
    unsigned short* Qb   = (unsigned short*)carve((size_t)Bb * NHh * VTSZ * 2);
    unsigned short* Kb   = (unsigned short*)carve((size_t)Bb * NHh * VTSZ * 2);
    unsigned short* Vt   = (unsigned short*)carve((size_t)Bb * NHh * VTSZ * 2);
    char* zend = base + off;
    unsigned short* act  = (unsigned short*)carve((size_t)Tt * FFf * 2);
    unsigned short* qkvw = (unsigned short*)carve((size_t)NLAY * 768 * KP * 2);
    unsigned short* owh  = (unsigned short*)carve((size_t)NLAY * 4 * 224 * 64 * 2);
    unsigned short* guw  = (unsigned short*)carve((size_t)NLAY * 1792 * KP * 2);
    unsigned short* dww  = (unsigned short*)carve((size_t)NLAY * 256 * 864 * 2);
    unsigned short* lmw  = (unsigned short*)carve((size_t)Vv * KP * 2);
    size_t need = off;

    if (ws_size >= need) {
        size_t zwords = (size_t)(zend - (char*)Qb) / 4;
        k_setup<<<5760, 256, 0, stream>>>(ids, emb, x, cos27, sin27,
            (unsigned int*)Qb, zwords, qkv_w, qkvw, o_w, owh,
            gate_w, up_w, guw, down_w, dww, lm_w, lmw);

        for (int l = 0; l < NLAY; ++l) {
            k_qkv64<<<dim3(32, 12), 256, 0, stream>>>(
                x, qkvw + (size_t)l * 768 * KP, ln1_w + (size_t)l * Dm,
                cos27, sin27, Qb, Kb, Vt);
            k_attn_o16<<<dim3(64, NHh, Bb), 256, 0, stream>>>(
                Qb, Kb, Vt, owh + (size_t)l * 4 * 224 * 64, x);
            k_gateup64<<<dim3(32, 28), 256, 0, stream>>>(
                x, guw + (size_t)l * 1792 * KP, ln2_w + (size_t)l * Dm, act);
            k_gemm_s<<<dim3(32, 4), 256, 0, stream>>>(
                act, dww + (size_t)l * 256 * 864, x, Dm, 864);
        }
        k_gemm_f<0, true><<<dim3(16, 250), 256, 0, stream>>>(
            x, lmw, nullptr, out, norm_w, Vv, KP);
    } else {
        // -------- legacy fp32 fallback --------
        float* ws = (float*)d_ws;
        size_t o2 = 0;
        float* x2    = ws + o2; o2 += (size_t)Tt * Dm;
        float* h2    = ws + o2; o2 += (size_t)Tt * Dm;
        float* qkv2  = ws + o2; o2 += (size_t)Tt * QKVW;
        float* aout2 = ws + o2; o2 += (size_t)Tt * Dm;
        float* act2  = ws + o2; o2 += (size_t)Tt * FFf;
        float* cosb2 = ws + o2; o2 += (size_t)Ss * HDd;
        float* sinb2 = ws + o2; o2 += (size_t)Ss * HDd;

        k_embed<<<Tt, 256, 0, stream>>>(ids, emb, x2);
        k_rope_tables<<<Ss, 64, 0, stream>>>(cosb2, sinb2);
        dim3 blk(TS, TS);
        for (int l = 0; l < NLAY; ++l) {
            k_rmsnorm<<<Tt, 64, 0, stream>>>(x2, ln1_w + (size_t)l * Dm, h2);
            k_gemm<<<dim3((QKVW + TS - 1) / TS, (Tt + TS - 1) / TS), blk, 0, stream>>>(
                h2, qkv_w + (size_t)l * QKVW * Dm, nullptr, qkv2, Tt, QKVW, Dm);
            k_rope<<<Tt, 256, 0, stream>>>(qkv2, cosb2, sinb2);
            k_attn<<<dim3(Ss, NHh, Bb), 256, 0, stream>>>(qkv2, aout2);
            k_gemm<<<dim3((Dm + TS - 1) / TS, (Tt + TS - 1) / TS), blk, 0, stream>>>(
                aout2, o_w + (size_t)l * Dm * Dm, x2, x2, Tt, Dm, Dm);
            k_rmsnorm<<<Tt, 64, 0, stream>>>(x2, ln2_w + (size_t)l * Dm, h2);
            k_gateup<<<dim3((FFf + TS - 1) / TS, (Tt + TS - 1) / TS), blk, 0, stream>>>(
                h2, gate_w + (size_t)l * FFf * Dm, up_w + (size_t)l * FFf * Dm, act2, Tt, FFf, Dm);
            k_gemm<<<dim3((Dm + TS - 1) / TS, (Tt + TS - 1) / TS), blk, 0, stream>>>(
                act2, down_w + (size_t)l * Dm * FFf, x2, x2, Tt, Dm, FFf);
        }
        k_rmsnorm<<<Tt, 64, 0, stream>>>(x2, norm_w, h2);
        k_gemm<<<dim3((Vv + TS - 1) / TS, (Tt + TS - 1) / TS), blk, 0, stream>>>(
            h2, lm_w, nullptr, out, Tt, Vv, Dm);
    }
}

// Round 14
// 868.804 us; speedup vs baseline: 1.6783x; 1.0433x over previous
//
#include <hip/hip_runtime.h>
#include <math.h>

#define Vv 32000
#define Dm 216
#define NLAY 11
#define NHh 4
#define HDd 54
#define FFf 864
#define Bb 2
#define Ss 1024
#define Tt (Bb*Ss)
#define EPSf 1e-5f
#define QKVW 648   // 3*Dm
#define KP 224     // K=216 padded to multiple of 32
#define HDP 64     // head dim padded
#define VTSZ (Ss*HDP)

typedef __attribute__((ext_vector_type(8))) short short8;
typedef __attribute__((ext_vector_type(8))) unsigned short ushort8;
typedef __attribute__((ext_vector_type(4))) float f32x4;

__device__ __forceinline__ unsigned short f2bf(float f) {
    unsigned int u = __float_as_uint(f);
    return (unsigned short)((u + 0x7fffu + ((u >> 16) & 1u)) >> 16);
}
__device__ __forceinline__ float bf2f(unsigned short u) {
    return __uint_as_float(((unsigned int)u) << 16);
}

// ================= setup: embed + tables + zero + weight convs (one launch) ========
__device__ void dev_convw(int relb, int nblk, const float* __restrict__ src,
                          unsigned short* __restrict__ dst,
                          int L, int N, int K, int Npad, int Kp, int rstride,
                          long dls, long doff) {
    size_t total = (size_t)L * Npad * Kp;
    for (size_t idx = (size_t)relb * 256 + threadIdx.x; idx < total;
         idx += (size_t)nblk * 256) {
        int k = (int)(idx % Kp);
        size_t rr = idx / Kp;
        int n = (int)(rr % Npad);
        int l = (int)(rr / Npad);
        float v = (n < N && k < K) ? src[((size_t)l * N + n) * K + k] : 0.f;
        dst[(size_t)l * dls + doff + (size_t)n * rstride + k] = f2bf(v);
    }
}

__device__ void dev_convqkv(int relb, int nblk, const float* __restrict__ src,
                            unsigned short* __restrict__ dst) {
    size_t total = (size_t)NLAY * 768 * KP;
    for (size_t idx = (size_t)relb * 256 + threadIdx.x; idx < total;
         idx += (size_t)nblk * 256) {
        int kk2 = (int)(idx % KP);
        size_t rr = idx / KP;
        int nr = (int)(rr % 768);
        int l = (int)(rr / 768);
        float v = 0.f;
        if (nr < 648 && kk2 < 216) {
            int srow;
            float sc = 1.f;
            if (nr < 432) {
                int which = nr >= 216;
                int cih = nr - which * 216;
                int head = cih / 54, dd = cih % 54;
                int j = dd >> 1, odd = dd & 1;
                srow = which * 216 + head * 54 + j + odd * 27;
                if (!which) sc = 0.13608276348795434f; // 54^-0.5 folded into q
            } else srow = nr;
            v = src[((size_t)l * QKVW + srow) * 216 + kk2] * sc;
        }
        dst[idx] = f2bf(v);
    }
}

// head-sliced o-weight: owh[l][h][n 224][k 64] = o_w[l][n][h*54+k] (zero padded)
__device__ void dev_convowh(int relb, int nblk, const float* __restrict__ src,
                            unsigned short* __restrict__ dst) {
    size_t total = (size_t)NLAY * 4 * 224 * 64;
    for (size_t idx = (size_t)relb * 256 + threadIdx.x; idx < total;
         idx += (size_t)nblk * 256) {
        int kk = (int)(idx & 63);
        size_t rr = idx >> 6;
        int n = (int)(rr % 224);
        size_t rh = rr / 224;
        int h = (int)(rh & 3);
        int l = (int)(rh >> 2);
        float v = (n < 216 && kk < 54)
            ? src[((size_t)l * 216 + n) * 216 + h * 54 + kk] : 0.f;
        dst[idx] = f2bf(v);
    }
}

__global__ void k_setup(const int* __restrict__ ids, const float* __restrict__ emb,
                        float* __restrict__ x,
                        float* __restrict__ cost, float* __restrict__ sint,
                        unsigned int* __restrict__ zp, size_t zwords,
                        const float* __restrict__ qkv_w, unsigned short* __restrict__ qkvw,
                        const float* __restrict__ o_w, unsigned short* __restrict__ owh,
                        const float* __restrict__ gate_w, const float* __restrict__ up_w,
                        unsigned short* __restrict__ guw,
                        const float* __restrict__ down_w, unsigned short* __restrict__ dww,
                        const float* __restrict__ lm_w, unsigned short* __restrict__ lmw)
{
    const int b = blockIdx.x;
    const int tid = threadIdx.x;
    if (b < 2048) {
        int id = ids[b];
        for (int d = tid; d < Dm; d += 256)
            x[(size_t)b * Dm + d] = emb[(size_t)id * Dm + d];
    } else if (b < 2176) {
        for (int idx = (b - 2048) * 256 + tid; idx < 1024 * 27; idx += 128 * 256) {
            int s = idx / 27, j = idx % 27;
            float inv = powf(10000.0f, -2.0f * (float)j / 54.0f);
            float f = (float)s * inv;
            cost[s * 27 + j] = cosf(f);
            sint[s * 27 + j] = sinf(f);
        }
    } else if (b < 2432) {
        for (size_t i = (size_t)(b - 2176) * 256 + tid; i < zwords; i += (size_t)256 * 256)
            zp[i] = 0;
    } else if (b < 2944) {
        dev_convqkv(b - 2432, 512, qkv_w, qkvw);
    } else if (b < 3200) {
        dev_convowh(b - 2944, 256, o_w, owh);
    } else if (b < 3712) {
        dev_convw(b - 3200, 512, gate_w, guw, NLAY, FFf, Dm, 896, KP, 2 * KP, 1792L * KP, 0);
    } else if (b < 4224) {
        dev_convw(b - 3712, 512, up_w, guw, NLAY, FFf, Dm, 896, KP, 2 * KP, 1792L * KP, KP);
    } else if (b < 4736) {
        dev_convw(b - 4224, 512, down_w, dww, NLAY, Dm, FFf, 256, 864, 864, 256L * 864, 0);
    } else {
        dev_convw(b - 4736, 1024, lm_w, lmw, 1, Vv, Dm, Vv, KP, KP, (long)Vv * KP, 0);
    }
}

// ================= shared phase helpers (proven rounds 6-13) =================
__device__ __forceinline__ void normpro(const float* __restrict__ x,
                                        const float* __restrict__ lnw, int m0,
                                        float* rsl, float* lnl, int tid) {
    __syncthreads();
    if (tid < 224) lnl[tid] = (tid < 216) ? lnw[tid] : 0.f;
    if (tid < 128) {
        int row = tid >> 1, half = tid & 1;
        const float* xr = x + (size_t)(m0 + row) * Dm + half * 108;
        float ss = 0.f;
        #pragma unroll
        for (int q = 0; q < 27; ++q) {
            float4 v = *(const float4*)(xr + q * 4);
            ss += v.x * v.x + v.y * v.y + v.z * v.z + v.w * v.w;
        }
        ss += __shfl_xor(ss, 1, 64);
        if (half == 0) rsl[row] = rsqrtf(ss / 216.f + EPSf);
    }
    __syncthreads();
}

__device__ __forceinline__ ushort8 normA(const float* __restrict__ x,
                                         const float* rsl, const float* lnl,
                                         int m0, int row, int base) {
    ushort8 o;
    if (base < 216) {
        const float* pp = x + (size_t)(m0 + row) * Dm + base;
        float r = rsl[row];
        float4 v0 = *(const float4*)pp;
        float4 v1 = *(const float4*)(pp + 4);
        o[0] = f2bf(v0.x * r * lnl[base + 0]);
        o[1] = f2bf(v0.y * r * lnl[base + 1]);
        o[2] = f2bf(v0.z * r * lnl[base + 2]);
        o[3] = f2bf(v0.w * r * lnl[base + 3]);
        o[4] = f2bf(v1.x * r * lnl[base + 4]);
        o[5] = f2bf(v1.y * r * lnl[base + 5]);
        o[6] = f2bf(v1.z * r * lnl[base + 6]);
        o[7] = f2bf(v1.w * r * lnl[base + 7]);
    } else {
        #pragma unroll
        for (int e = 0; e < 8; ++e) o[e] = 0;
    }
    return o;
}

// ================= qkv: 64x64 tiles, norm-fused A, rope/transpose epilogue =========
__global__ __launch_bounds__(256) void k_qkv64(
    const float* __restrict__ x, const unsigned short* __restrict__ W,
    const float* __restrict__ lnw,
    const float* __restrict__ cost, const float* __restrict__ sint,
    unsigned short* __restrict__ Qb, unsigned short* __restrict__ Kb,
    unsigned short* __restrict__ Vt)
{
    __shared__ __align__(16) unsigned char SM[17664];
    unsigned short* lA = (unsigned short*)SM;
    unsigned short* lB = (unsigned short*)(SM + 8192);
    float* rsl = (float*)(SM + 16384);
    float* lnl = (float*)(SM + 16640);
    const int tid = threadIdx.x;
    const int m0 = blockIdx.x * 64;
    const int n0 = blockIdx.y * 64;
    normpro(x, lnw, m0, rsl, lnl, tid);

    const int wid = tid >> 6, lane = tid & 63;
    const int wr = wid >> 1, wc = wid & 1;
    const int r = tid >> 2, kc = tid & 3;
    const int lo = (r >> 4) * 512 + (((kc << 4) | (r & 15)) << 3);

    ushort8 ra = normA(x, rsl, lnl, m0, r, kc * 8);
    ushort8 rb = *(const ushort8*)(W + (size_t)(n0 + r) * KP + kc * 8);
    *(ushort8*)&lA[lo] = ra;
    *(ushort8*)&lB[lo] = rb;
    __syncthreads();

    f32x4 acc[2][2] = {};
    int cur = 0;
    for (int step = 0; step < 7; ++step) {
        const bool more = step < 6;
        if (more) {
            const int k0 = (step + 1) << 5;
            ra = normA(x, rsl, lnl, m0, r, k0 + kc * 8);
            rb = *(const ushort8*)(W + (size_t)(n0 + r) * KP + k0 + kc * 8);
        }
        short8 af[2], bf2[2];
        #pragma unroll
        for (int f = 0; f < 2; ++f) {
            af[f] = *(const short8*)&lA[cur * 2048 + (wr * 2 + f) * 512 + lane * 8];
            bf2[f] = *(const short8*)&lB[cur * 2048 + (wc * 2 + f) * 512 + lane * 8];
        }
        #pragma unroll
        for (int fm = 0; fm < 2; ++fm)
            #pragma unroll
            for (int fn = 0; fn < 2; ++fn)
                acc[fm][fn] = __builtin_amdgcn_mfma_f32_16x16x32_bf16(af[fm], bf2[fn], acc[fm][fn], 0, 0, 0);
        if (more) {
            const int nxt = cur ^ 1;
            *(ushort8*)&lA[nxt * 2048 + lo] = ra;
            *(ushort8*)&lB[nxt * 2048 + lo] = rb;
            __syncthreads();
            cur = nxt;
        }
    }

    const int lc16 = lane & 15, lg = lane >> 4;
    #pragma unroll
    for (int fm = 0; fm < 2; ++fm) {
        const int mrow = m0 + wr * 32 + fm * 16 + lg * 4;
        const int b = mrow >> 10;
        const int st0 = mrow & 1023;
        #pragma unroll
        for (int fn = 0; fn < 2; ++fn) {
            const int ncol = n0 + wc * 32 + fn * 16 + lc16;
            float v0 = acc[fm][fn][0], v1 = acc[fm][fn][1];
            float v2 = acc[fm][fn][2], v3 = acc[fm][fn][3];
            float p0 = __shfl_xor(v0, 1, 64);
            float p1 = __shfl_xor(v1, 1, 64);
            float p2 = __shfl_xor(v2, 1, 64);
            float p3 = __shfl_xor(v3, 1, 64);
            if (ncol < 432) {
                int which = ncol >= 216;
                int cih = ncol - which * 216;
                int head = cih / 54, dd = cih % 54;
                int j = dd >> 1;
                bool odd = dd & 1;
                unsigned short* dst = (which ? Kb : Qb) +
                    ((size_t)(b * NHh + head) * Ss + st0) * HDP + dd;
                float vv[4] = {v0, v1, v2, v3};
                float pp[4] = {p0, p1, p2, p3};
                #pragma unroll
                for (int i = 0; i < 4; ++i) {
                    float c = cost[(st0 + i) * 27 + j];
                    float sn = sint[(st0 + i) * 27 + j];
                    float o = odd ? (vv[i] * c + pp[i] * sn) : (vv[i] * c - pp[i] * sn);
                    dst[(size_t)i * HDP] = f2bf(o);
                }
            } else if (ncol < 648) {
                int d = ncol - 432;
                int head = d / 54, dd = d % 54;
                ushort4 pk;
                pk.x = f2bf(v0); pk.y = f2bf(v1); pk.z = f2bf(v2); pk.w = f2bf(v3);
                *(ushort4*)(Vt + (size_t)(b * NHh + head) * VTSZ + (size_t)dd * Ss + st0) = pk;
            }
        }
    }
}

// ================= gate/up: 64x64 tiles, norm-fused A, silu epilogue =========
__global__ __launch_bounds__(256) void k_gateup64(
    const float* __restrict__ x, const unsigned short* __restrict__ W,
    const float* __restrict__ lnw, unsigned short* __restrict__ act)
{
    __shared__ __align__(16) unsigned char SM[17664];
    unsigned short* lA = (unsigned short*)SM;
    unsigned short* lB = (unsigned short*)(SM + 8192);
    float* rsl = (float*)(SM + 16384);
    float* lnl = (float*)(SM + 16640);
    const int tid = threadIdx.x;
    const int m0 = blockIdx.x * 64;
    const int n0 = blockIdx.y * 64;
    normpro(x, lnw, m0, rsl, lnl, tid);

    const int wid = tid >> 6, lane = tid & 63;
    const int wr = wid >> 1, wc = wid & 1;
    const int r = tid >> 2, kc = tid & 3;
    const int lo = (r >> 4) * 512 + (((kc << 4) | (r & 15)) << 3);

    ushort8 ra = normA(x, rsl, lnl, m0, r, kc * 8);
    ushort8 rb = *(const ushort8*)(W + (size_t)(n0 + r) * KP + kc * 8);
    *(ushort8*)&lA[lo] = ra;
    *(ushort8*)&lB[lo] = rb;
    __syncthreads();

    f32x4 acc[2][2] = {};
    int cur = 0;
    for (int step = 0; step < 7; ++step) {
        const bool more = step < 6;
        if (more) {
            const int k0 = (step + 1) << 5;
            ra = normA(x, rsl, lnl, m0, r, k0 + kc * 8);
            rb = *(const ushort8*)(W + (size_t)(n0 + r) * KP + k0 + kc * 8);
        }
        short8 af[2], bf2[2];
        #pragma unroll
        for (int f = 0; f < 2; ++f) {
            af[f] = *(const short8*)&lA[cur * 2048 + (wr * 2 + f) * 512 + lane * 8];
            bf2[f] = *(const short8*)&lB[cur * 2048 + (wc * 2 + f) * 512 + lane * 8];
        }
        #pragma unroll
        for (int fm = 0; fm < 2; ++fm)
            #pragma unroll
            for (int fn = 0; fn < 2; ++fn)
                acc[fm][fn] = __builtin_amdgcn_mfma_f32_16x16x32_bf16(af[fm], bf2[fn], acc[fm][fn], 0, 0, 0);
        if (more) {
            const int nxt = cur ^ 1;
            *(ushort8*)&lA[nxt * 2048 + lo] = ra;
            *(ushort8*)&lB[nxt * 2048 + lo] = rb;
            __syncthreads();
            cur = nxt;
        }
    }

    const int lc16 = lane & 15, lg = lane >> 4;
    #pragma unroll
    for (int fm = 0; fm < 2; ++fm) {
        const int mrow = m0 + wr * 32 + fm * 16 + lg * 4;
        #pragma unroll
        for (int fn = 0; fn < 2; ++fn) {
            const int ncol = n0 + wc * 32 + fn * 16 + lc16;
            #pragma unroll
            for (int i = 0; i < 4; ++i) {
                float v = acc[fm][fn][i];
                float p = __shfl_xor(v, 1, 64);
                if ((lc16 & 1) == 0 && ncol < 1728) {
                    float y = v / (1.f + __expf(-v)) * p;
                    act[(size_t)(mrow + i) * 864 + (ncol >> 1)] = f2bf(y);
                }
            }
        }
    }
}

// ====== down GEMM: 64x64 tile, split-K=2 (grid z), atomicAdd into x ======
__global__ __launch_bounds__(256) void k_gemm_s2(
    const unsigned short* __restrict__ A, const unsigned short* __restrict__ W,
    float* __restrict__ xio, int N, int Kp)
{
    __shared__ __align__(16) unsigned short lA[2][2048];
    __shared__ __align__(16) unsigned short lB[2][2048];
    const int tid = threadIdx.x;
    const int m0 = blockIdx.x * 64, n0 = blockIdx.y * 64;
    const int kz = blockIdx.z;
    const int nsteps_tot = Kp >> 5;                 // 27 for K=864
    const int s0 = kz ? (nsteps_tot / 2 + 1) : 0;   // kz0: [0,14), kz1: [14,27)
    const int s1 = kz ? nsteps_tot : (nsteps_tot / 2 + 1);
    const int nsteps = s1 - s0;
    const int wid = tid >> 6, lane = tid & 63;
    const int wr = wid >> 1, wc = wid & 1;
    const int r = tid >> 2, kc = tid & 3;
    const int lo = (r >> 4) * 512 + (((kc << 4) | (r & 15)) << 3);

    ushort8 ra = *(const ushort8*)(A + (size_t)(m0 + r) * Kp + s0 * 32 + kc * 8);
    ushort8 rb = *(const ushort8*)(W + (size_t)(n0 + r) * Kp + s0 * 32 + kc * 8);
    *(ushort8*)&lA[0][lo] = ra;
    *(ushort8*)&lB[0][lo] = rb;
    __syncthreads();

    f32x4 acc[2][2] = {};
    int cur = 0;
    for (int step = 0; step < nsteps; ++step) {
        const bool more = (step + 1) < nsteps;
        if (more) {
            const int k0 = (s0 + step + 1) << 5;
            ra = *(const ushort8*)(A + (size_t)(m0 + r) * Kp + k0 + kc * 8);
            rb = *(const ushort8*)(W + (size_t)(n0 + r) * Kp + k0 + kc * 8);
        }
        short8 af[2], bf2[2];
        #pragma unroll
        for (int f = 0; f < 2; ++f) {
            af[f] = *(const short8*)&lA[cur][(wr * 2 + f) * 512 + lane * 8];
            bf2[f] = *(const short8*)&lB[cur][(wc * 2 + f) * 512 + lane * 8];
        }
        #pragma unroll
        for (int fm = 0; fm < 2; ++fm)
            #pragma unroll
            for (int fn = 0; fn < 2; ++fn)
                acc[fm][fn] = __builtin_amdgcn_mfma_f32_16x16x32_bf16(af[fm], bf2[fn], acc[fm][fn], 0, 0, 0);
        if (more) {
            const int nxt = cur ^ 1;
            *(ushort8*)&lA[nxt][lo] = ra;
            *(ushort8*)&lB[nxt][lo] = rb;
            __syncthreads();
            cur = nxt;
        }
    }

    #pragma unroll
    for (int fm = 0; fm < 2; ++fm) {
        const int mrow = m0 + wr * 32 + fm * 16 + (lane >> 4) * 4;
        #pragma unroll
        for (int fn = 0; fn < 2; ++fn) {
            const int ncol = n0 + wc * 32 + fn * 16 + (lane & 15);
            if (ncol < N) {
                #pragma unroll
                for (int i = 0; i < 4; ++i) {
                    const size_t oi = (size_t)(mrow + i) * N + ncol;
                    atomicAdd(&xio[oi], acc[fm][fn][i]);
                }
            }
        }
    }
}

// ===== attention (16 q-rows, 4-wave kv-split, wave-private staging) + fused o-proj =
__global__ __launch_bounds__(256) void k_attn_o16(
    const unsigned short* __restrict__ Qb, const unsigned short* __restrict__ Kb,
    const unsigned short* __restrict__ Vt, const unsigned short* __restrict__ owh_l,
    float* __restrict__ x)
{
    __shared__ __align__(16) unsigned char SM[38912];
    const int tid = threadIdx.x;
    const int qu = blockIdx.x, h = blockIdx.y, b = blockIdx.z;
    const int bh = b * NHh + h;
    const int q0w = qu * 16;
    const int w = tid >> 6, lane = tid & 63;
    const int lc = lane & 15, lg = lane >> 4;

    unsigned short* Klw = (unsigned short*)(SM + w * 4096);          // 32k x 64d frag-order
    unsigned short* Vlw = (unsigned short*)(SM + 16384 + w * 4096);  // 64d x 32k frag-order
    unsigned short* Plw = (unsigned short*)(SM + 32768 + w * 1024);  // 16q x 32k A-frag
    unsigned short* Ol  = (unsigned short*)(SM + 36864);             // 16q x 64k A-frag

    const unsigned short* Qp = Qb + (size_t)bh * VTSZ;
    const unsigned short* Kpp = Kb + (size_t)bh * VTSZ;
    const unsigned short* Vp = Vt + (size_t)bh * VTSZ;
    const unsigned short* owh_h = owh_l + (size_t)h * 224 * 64;

    short8 qa[2];
    #pragma unroll
    for (int half = 0; half < 2; ++half)
        qa[half] = *(const short8*)(Qp + (size_t)(q0w + lc) * HDP + lg * 8 + half * 32);

    f32x4 o4[4] = {};
    float mreg[4] = {-3e38f, -3e38f, -3e38f, -3e38f};
    float lreg[4] = {0.f, 0.f, 0.f, 0.f};

    const int nt = (q0w + 15) / 32 + 1;
    for (int t = w; t < nt; t += 4) {
        const int kv0 = t * 32;
        for (int c = lane; c < 512; c += 64) {
            if (c < 256) {
                int sub = c >> 6;
                int kgrp = sub >> 1, dhalf = sub & 1;
                int dchunk = (c >> 4) & 3, krow = c & 15;
                *(ushort8*)&Klw[sub * 512 + (c & 63) * 8] =
                    *(const ushort8*)(Kpp + (size_t)(kv0 + kgrp * 16 + krow) * HDP + dhalf * 32 + dchunk * 8);
            } else {
                int c2 = c - 256;
                int dgrp = c2 >> 6;
                int kchunk = (c2 >> 4) & 3, dcol = c2 & 15;
                *(ushort8*)&Vlw[dgrp * 512 + (c2 & 63) * 8] =
                    *(const ushort8*)(Vp + (size_t)(dgrp * 16 + dcol) * Ss + kv0 + kchunk * 8);
            }
        }
        f32x4 s4[2] = {};
        #pragma unroll
        for (int dhalf = 0; dhalf < 2; ++dhalf) {
            #pragma unroll
            for (int kgrp = 0; kgrp < 2; ++kgrp) {
                short8 kf = *(const short8*)&Klw[(kgrp * 2 + dhalf) * 512 + lane * 8];
                s4[kgrp] = __builtin_amdgcn_mfma_f32_16x16x32_bf16(qa[dhalf], kf, s4[kgrp], 0, 0, 0);
            }
        }
        if (kv0 + 31 > q0w) {
            #pragma unroll
            for (int kgrp = 0; kgrp < 2; ++kgrp) {
                int kg = kv0 + kgrp * 16 + lc;
                #pragma unroll
                for (int rr = 0; rr < 4; ++rr) {
                    int qg = q0w + lg * 4 + rr;
                    if (kg > qg) s4[kgrp][rr] = -3e38f;
                }
            }
        }
        #pragma unroll
        for (int rr = 0; rr < 4; ++rr) {
            float rm = fmaxf(s4[0][rr], s4[1][rr]);
            #pragma unroll
            for (int msk = 1; msk < 16; msk <<= 1)
                rm = fmaxf(rm, __shfl_xor(rm, msk, 64));
            float mn = fmaxf(mreg[rr], rm);
            float esc = __expf(mreg[rr] - mn);
            mreg[rr] = mn;
            float e0 = __expf(s4[0][rr] - mn);
            float e1 = __expf(s4[1][rr] - mn);
            float rs = e0 + e1;
            #pragma unroll
            for (int msk = 1; msk < 16; msk <<= 1)
                rs += __shfl_xor(rs, msk, 64);
            lreg[rr] = lreg[rr] * esc + rs;
            #pragma unroll
            for (int db = 0; db < 4; ++db) o4[db][rr] *= esc;
            int q = lg * 4 + rr;
            Plw[(((lc >> 3)) * 16 + q) * 8 + (lc & 7)] = f2bf(e0);
            Plw[((2 + (lc >> 3)) * 16 + q) * 8 + (lc & 7)] = f2bf(e1);
        }
        short8 pa = *(const short8*)&Plw[(lg * 16 + lc) * 8];
        #pragma unroll
        for (int db = 0; db < 4; ++db) {
            short8 vf = *(const short8*)&Vlw[db * 512 + lane * 8];
            o4[db] = __builtin_amdgcn_mfma_f32_16x16x32_bf16(pa, vf, o4[db], 0, 0, 0);
        }
    }

    __syncthreads();
    float* mg = (float*)SM;
    const int slot = (w * 64 + lane) * 25;
    #pragma unroll
    for (int rr = 0; rr < 4; ++rr) { mg[slot + rr] = mreg[rr]; mg[slot + 4 + rr] = lreg[rr]; }
    #pragma unroll
    for (int db = 0; db < 4; ++db)
        #pragma unroll
        for (int rr = 0; rr < 4; ++rr) mg[slot + 8 + db * 4 + rr] = o4[db][rr];
    __syncthreads();
    if (w == 0) {
        #pragma unroll
        for (int rr = 0; rr < 4; ++rr) {
            float m = mreg[rr];
            #pragma unroll
            for (int ww = 1; ww < 4; ++ww)
                m = fmaxf(m, mg[(ww * 64 + lane) * 25 + rr]);
            float eself = __expf(mreg[rr] - m);
            float l = lreg[rr] * eself;
            float oc[4];
            #pragma unroll
            for (int db = 0; db < 4; ++db) oc[db] = o4[db][rr] * eself;
            #pragma unroll
            for (int ww = 1; ww < 4; ++ww) {
                int sl = (ww * 64 + lane) * 25;
                float e = __expf(mg[sl + rr] - m);
                l += mg[sl + 4 + rr] * e;
                #pragma unroll
                for (int db = 0; db < 4; ++db) oc[db] += mg[sl + 8 + db * 4 + rr] * e;
            }
            float inv = 1.f / l;
            int q = lg * 4 + rr;
            #pragma unroll
            for (int db = 0; db < 4; ++db) {
                int kchunk = db * 2 + (lc >> 3);
                Ol[(kchunk * 16 + q) * 8 + (lc & 7)] = f2bf(oc[db] * inv);
            }
        }
    }
    __syncthreads();

    f32x4 oacc[4] = {};
    #pragma unroll
    for (int ks = 0; ks < 2; ++ks) {
        short8 afr = *(const short8*)&Ol[ks * 512 + lane * 8];
        #pragma unroll
        for (int gi = 0; gi < 4; ++gi) {
            int g = gi * 4 + w;
            if (g < 14) {
                int n = g * 16 + lc;
                short8 bfr = *(const short8*)(owh_h + (size_t)n * 64 + ks * 32 + lg * 8);
                oacc[gi] = __builtin_amdgcn_mfma_f32_16x16x32_bf16(afr, bfr, oacc[gi], 0, 0, 0);
            }
        }
    }
    #pragma unroll
    for (int gi = 0; gi < 4; ++gi) {
        int g = gi * 4 + w;
        if (g < 14) {
            int col = g * 16 + lc;
            if (col < 216) {
                #pragma unroll
                for (int i = 0; i < 4; ++i) {
                    int row = b * Ss + q0w + lg * 4 + i;
                    atomicAdd(&x[(size_t)row * Dm + col], oacc[gi][i]);
                }
            }
        }
    }
}

// ================= fused MFMA GEMM (128x128) — LM head w/ norm-A ==========
template<int OUTM, bool NORMA>
__global__ __launch_bounds__(256, 2) void k_gemm_f(
    const void* __restrict__ Av, const unsigned short* __restrict__ W,
    const float* __restrict__ res, void* __restrict__ outv,
    const float* __restrict__ lnw, int N, int Kp)
{
    __shared__ __align__(16) unsigned short lds[2][2][4096];
    __shared__ float rsl[128];
    __shared__ float lnl[224];
    const int tid = threadIdx.x;
    const int m0 = blockIdx.x * 128;
    const int n0 = blockIdx.y * 128;
    const int wid = tid >> 6, lane = tid & 63;
    const int wr = wid >> 1, wc = wid & 1;
    const int nsteps = Kp >> 5;

    if constexpr (NORMA) {
        const float* Af = (const float*)Av;
        if (tid < 224) lnl[tid] = (tid < 216) ? lnw[tid] : 0.f;
        int row = tid >> 1, half = tid & 1;
        const float* xr = Af + (size_t)(m0 + row) * 216 + half * 108;
        float ss = 0.f;
        #pragma unroll
        for (int q = 0; q < 27; ++q) {
            float4 v = *(const float4*)(xr + q * 4);
            ss += v.x * v.x + v.y * v.y + v.z * v.z + v.w * v.w;
        }
        ss += __shfl_xor(ss, 1, 64);
        if (half == 0) rsl[row] = rsqrtf(ss / 216.f + EPSf);
        __syncthreads();
    }

    const int i0 = tid, i1 = tid + 256;
    const int rA0 = i0 >> 2, cA0 = i0 & 3;
    const int rA1 = i1 >> 2, cA1 = i1 & 3;
    const int lo0 = (rA0 >> 4) * 512 + (((cA0 << 4) | (rA0 & 15)) << 3);
    const int lo1 = (rA1 >> 4) * 512 + (((cA1 << 4) | (rA1 & 15)) << 3);

    auto loadA = [&](int row, int base) -> ushort8 {
        ushort8 o;
        if constexpr (NORMA) {
            if (base < 216) {
                const float* p = (const float*)Av + (size_t)(m0 + row) * 216 + base;
                float r = rsl[row];
                float4 v0 = *(const float4*)p;
                float4 v1 = *(const float4*)(p + 4);
                o[0] = f2bf(v0.x * r * lnl[base + 0]);
                o[1] = f2bf(v0.y * r * lnl[base + 1]);
                o[2] = f2bf(v0.z * r * lnl[base + 2]);
                o[3] = f2bf(v0.w * r * lnl[base + 3]);
                o[4] = f2bf(v1.x * r * lnl[base + 4]);
                o[5] = f2bf(v1.y * r * lnl[base + 5]);
                o[6] = f2bf(v1.z * r * lnl[base + 6]);
                o[7] = f2bf(v1.w * r * lnl[base + 7]);
            } else {
                #pragma unroll
                for (int e = 0; e < 8; ++e) o[e] = 0;
            }
        } else {
            o = *(const ushort8*)((const unsigned short*)Av + (size_t)(m0 + row) * Kp + base);
        }
        return o;
    };

    ushort8 ra0, ra1, rb0, rb1;
    ra0 = loadA(rA0, cA0 * 8);
    ra1 = loadA(rA1, cA1 * 8);
    rb0 = *(const ushort8*)(W + (size_t)(n0 + rA0) * Kp + cA0 * 8);
    rb1 = *(const ushort8*)(W + (size_t)(n0 + rA1) * Kp + cA1 * 8);
    *(ushort8*)&lds[0][0][lo0] = ra0;
    *(ushort8*)&lds[0][0][lo1] = ra1;
    *(ushort8*)&lds[0][1][lo0] = rb0;
    *(ushort8*)&lds[0][1][lo1] = rb1;
    __syncthreads();

    f32x4 acc[4][4] = {};
    int cur = 0;
    for (int step = 0; step < nsteps; ++step) {
        const bool more = (step + 1) < nsteps;
        if (more) {
            const int k0 = (step + 1) << 5;
            ra0 = loadA(rA0, k0 + cA0 * 8);
            ra1 = loadA(rA1, k0 + cA1 * 8);
            rb0 = *(const ushort8*)(W + (size_t)(n0 + rA0) * Kp + k0 + cA0 * 8);
            rb1 = *(const ushort8*)(W + (size_t)(n0 + rA1) * Kp + k0 + cA1 * 8);
        }
        short8 af[4], bf[4];
        #pragma unroll
        for (int f = 0; f < 4; ++f) {
            af[f] = *(const short8*)&lds[cur][0][(wr * 4 + f) * 512 + lane * 8];
            bf[f] = *(const short8*)&lds[cur][1][(wc * 4 + f) * 512 + lane * 8];
        }
        #pragma unroll
        for (int fm = 0; fm < 4; ++fm)
            #pragma unroll
            for (int fn = 0; fn < 4; ++fn)
                acc[fm][fn] = __builtin_amdgcn_mfma_f32_16x16x32_bf16(af[fm], bf[fn], acc[fm][fn], 0, 0, 0);
        if (more) {
            const int nxt = cur ^ 1;
            *(ushort8*)&lds[nxt][0][lo0] = ra0;
            *(ushort8*)&lds[nxt][0][lo1] = ra1;
            *(ushort8*)&lds[nxt][1][lo0] = rb0;
            *(ushort8*)&lds[nxt][1][lo1] = rb1;
            __syncthreads();
            cur = nxt;
        }
    }

    const int lc16 = lane & 15;
    #pragma unroll
    for (int fm = 0; fm < 4; ++fm) {
        const int mrow = m0 + wr * 64 + fm * 16 + (lane >> 4) * 4;
        #pragma unroll
        for (int fn = 0; fn < 4; ++fn) {
            const int ncol = n0 + wc * 64 + fn * 16 + lc16;
            if (ncol < N) {
                #pragma unroll
                for (int i = 0; i < 4; ++i) {
                    const size_t oi = (size_t)(mrow + i) * N + ncol;
                    float v = acc[fm][fn][i];
                    if (res) v += res[oi];
                    ((float*)outv)[oi] = v;
                }
            }
        }
    }
}

// ================= legacy fp32 fallback kernels =================
__global__ void k_embed(const int* __restrict__ ids, const float* __restrict__ emb,
                        float* __restrict__ x) {
    int t = blockIdx.x;
    int id = ids[t];
    for (int d = threadIdx.x; d < Dm; d += blockDim.x)
        x[(size_t)t * Dm + d] = emb[(size_t)id * Dm + d];
}

__global__ void k_rope_tables(float* __restrict__ cosb, float* __restrict__ sinb) {
    int s = blockIdx.x;
    for (int d = threadIdx.x; d < HDd; d += blockDim.x) {
        int j = d % (HDd / 2);
        float inv = powf(10000.0f, -2.0f * (float)j / (float)HDd);
        float f = (float)s * inv;
        cosb[s * HDd + d] = cosf(f);
        sinb[s * HDd + d] = sinf(f);
    }
}

__global__ void k_rmsnorm(const float* __restrict__ x, const float* __restrict__ w,
                          float* __restrict__ h) {
    int t = blockIdx.x;
    const float* xr = x + (size_t)t * Dm;
    float ss = 0.f;
    for (int d = threadIdx.x; d < Dm; d += 64) { float v = xr[d]; ss += v * v; }
    for (int o = 32; o; o >>= 1) ss += __shfl_down(ss, o, 64);
    float r = __shfl(ss, 0, 64);
    r = rsqrtf(r / (float)Dm + EPSf);
    for (int d = threadIdx.x; d < Dm; d += 64)
        h[(size_t)t * Dm + d] = xr[d] * r * w[d];
}

#define TS 16
__global__ void k_gemm(const float* __restrict__ A, const float* __restrict__ W,
                       const float* __restrict__ res, float* __restrict__ out,
                       int M, int N, int K) {
    __shared__ float As[TS][TS + 1];
    __shared__ float Wsm[TS][TS + 1];
    const int tx = threadIdx.x, ty = threadIdx.y;
    const int m = blockIdx.y * TS + ty;
    const int n = blockIdx.x * TS + tx;
    float acc = 0.f;
    for (int k0 = 0; k0 < K; k0 += TS) {
        int ka = k0 + tx;
        As[ty][tx] = (m < M && ka < K) ? A[(size_t)m * K + ka] : 0.f;
        int nw = blockIdx.x * TS + ty;
        Wsm[ty][tx] = (nw < N && ka < K) ? W[(size_t)nw * K + ka] : 0.f;
        __syncthreads();
        #pragma unroll
        for (int kk = 0; kk < TS; ++kk) acc += As[ty][kk] * Wsm[tx][kk];
        __syncthreads();
    }
    if (m < M && n < N) {
        float r = res ? res[(size_t)m * N + n] : 0.f;
        out[(size_t)m * N + n] = r + acc;
    }
}

__global__ void k_gateup(const float* __restrict__ A, const float* __restrict__ Wg,
                         const float* __restrict__ Wu, float* __restrict__ act,
                         int M, int N, int K) {
    __shared__ float As[TS][TS + 1];
    __shared__ float Gs[TS][TS + 1];
    __shared__ float Us[TS][TS + 1];
    const int tx = threadIdx.x, ty = threadIdx.y;
    const int m = blockIdx.y * TS + ty;
    const int n = blockIdx.x * TS + tx;
    float ag = 0.f, au = 0.f;
    for (int k0 = 0; k0 < K; k0 += TS) {
        int ka = k0 + tx;
        As[ty][tx] = (m < M && ka < K) ? A[(size_t)m * K + ka] : 0.f;
        int nw = blockIdx.x * TS + ty;
        Gs[ty][tx] = (nw < N && ka < K) ? Wg[(size_t)nw * K + ka] : 0.f;
        Us[ty][tx] = (nw < N && ka < K) ? Wu[(size_t)nw * K + ka] : 0.f;
        __syncthreads();
        #pragma unroll
        for (int kk = 0; kk < TS; ++kk) {
            ag += As[ty][kk] * Gs[tx][kk];
            au += As[ty][kk] * Us[tx][kk];
        }
        __syncthreads();
    }
    if (m < M && n < N) {
        float sg = ag / (1.f + expf(-ag));
        act[(size_t)m * N + n] = sg * au;
    }
}

__global__ void k_rope(float* __restrict__ qkv, const float* __restrict__ cosb,
                       const float* __restrict__ sinb) {
    const int t = blockIdx.x;
    const int s = t % Ss;
    float* base = qkv + (size_t)t * QKVW;
    const int HALF = HDd / 2;
    int i = threadIdx.x;
    if (i < 2 * NHh * HALF) {
        int which = i / (NHh * HALF);
        int rem = i % (NHh * HALF);
        int hh = rem / HALF;
        int d = rem % HALF;
        float* ptr = base + which * Dm + hh * HDd;
        float x1 = ptr[d], x2 = ptr[d + HALF];
        float c1 = cosb[s * HDd + d], s1 = sinb[s * HDd + d];
        float c2 = cosb[s * HDd + d + HALF], s2 = sinb[s * HDd + d + HALF];
        ptr[d]        = x1 * c1 - x2 * s1;
        ptr[d + HALF] = x2 * c2 + x1 * s2;
    }
}

__global__ void k_attn(const float* __restrict__ qkv, float* __restrict__ aout) {
    const int q = blockIdx.x, h = blockIdx.y, b = blockIdx.z;
    const int tid = threadIdx.x;
    __shared__ float p[Ss];
    __shared__ float qv[HDd];
    __shared__ float rmax[4], rsum[4];
    const size_t base = (size_t)b * Ss * QKVW;
    const float* qrow = qkv + base + (size_t)q * QKVW + h * HDd;
    if (tid < HDd) qv[tid] = qrow[tid];
    __syncthreads();
    const int nk = q + 1;
    const float scale = 0.13608276348795434f;
    float lmax = -3.0e38f;
    for (int k = tid; k < nk; k += 256) {
        const float* krow = qkv + base + (size_t)k * QKVW + Dm + h * HDd;
        float acc = 0.f;
        #pragma unroll
        for (int d = 0; d < HDd; ++d) acc += qv[d] * krow[d];
        acc *= scale;
        p[k] = acc;
        lmax = fmaxf(lmax, acc);
    }
    for (int o = 32; o; o >>= 1) lmax = fmaxf(lmax, __shfl_down(lmax, o, 64));
    if ((tid & 63) == 0) rmax[tid >> 6] = lmax;
    __syncthreads();
    const float m = fmaxf(fmaxf(rmax[0], rmax[1]), fmaxf(rmax[2], rmax[3]));
    float lsum = 0.f;
    for (int k = tid; k < nk; k += 256) {
        float e = expf(p[k] - m);
        p[k] = e;
        lsum += e;
    }
    for (int o = 32; o; o >>= 1) lsum += __shfl_down(lsum, o, 64);
    if ((tid & 63) == 0) rsum[tid >> 6] = lsum;
    __syncthreads();
    const float inv = 1.f / (rsum[0] + rsum[1] + rsum[2] + rsum[3]);
    for (int d = tid; d < HDd; d += 256) {
        const float* vcol = qkv + base + 2 * Dm + h * HDd + d;
        float acc = 0.f;
        for (int k = 0; k < nk; ++k) acc += p[k] * vcol[(size_t)k * QKVW];
        aout[(size_t)(b * Ss + q) * Dm + h * HDd + d] = acc * inv;
    }
}

// =====================================================================
extern "C" void kernel_launch(void* const* d_in, const int* in_sizes, int n_in,
                              void* d_out, int out_size, void* d_ws, size_t ws_size,
                              hipStream_t stream) {
    const int*   ids    = (const int*)d_in[0];
    const float* emb    = (const float*)d_in[1];
    const float* ln1_w  = (const float*)d_in[2];
    const float* qkv_w  = (const float*)d_in[3];
    const float* o_w    = (const float*)d_in[4];
    const float* ln2_w  = (const float*)d_in[5];
    const float* gate_w = (const float*)d_in[6];
    const float* up_w   = (const float*)d_in[7];
    const float* down_w = (const float*)d_in[8];
    const float* norm_w = (const float*)d_in[9];
    const float* lm_w   = (const float*)d_in[10];
    float* out = (float*)d_out;

    char* base = (char*)d_ws;
    size_t off = 0;
    auto carve = [&](size_t bytes) -> char* {
        char* p = base + off;
        off += (bytes + 255) & ~(size_t)255;
        return p;
    };

    // fp32 buffers
    float* x     = (float*)carve((size_t)Tt * Dm * 4);
    float* cos27 = (float*)carve((size_t)Ss * 27 * 4);
    float* sin27 = (float*)carve((size_t)Ss * 27 * 4);
    // bf16 buffers (Qb..Vt contiguous, pads zeroed every call by setup)
    unsigned short* Qb   = (unsigned short*)carve((size_t)Bb * NHh * VTSZ * 2);
    unsigned short* Kb   = (unsigned short*)carve((size_t)Bb * NHh * VTSZ * 2);
    unsigned short* Vt   = (unsigned short*)carve((size_t)Bb * NHh * VTSZ * 2);
    char* zend = base + off;
    unsigned short* act  = (unsigned short*)carve((size_t)Tt * FFf * 2);
    unsigned short* qkvw = (unsigned short*)carve((size_t)NLAY * 768 * KP * 2);
    unsigned short* owh  = (unsigned short*)carve((size_t)NLAY * 4 * 224 * 64 * 2);
    unsigned short* guw  = (unsigned short*)carve((size_t)NLAY * 1792 * KP * 2);
    unsigned short* dww  = (unsigned short*)carve((size_t)NLAY * 256 * 864 * 2);
    unsigned short* lmw  = (unsigned short*)carve((size_t)Vv * KP * 2);
    size_t need = off;

    if (ws_size >= need) {
        size_t zwords = (size_t)(zend - (char*)Qb) / 4;
        k_setup<<<5760, 256, 0, stream>>>(ids, emb, x, cos27, sin27,
            (unsigned int*)Qb, zwords, qkv_w, qkvw, o_w, owh,
            gate_w, up_w, guw, down_w, dww, lm_w, lmw);

        for (int l = 0; l < NLAY; ++l) {
            k_qkv64<<<dim3(32, 12), 256, 0, stream>>>(
                x, qkvw + (size_t)l * 768 * KP, ln1_w + (size_t)l * Dm,
                cos27, sin27, Qb, Kb, Vt);
            k_attn_o16<<<dim3(64, NHh, Bb), 256, 0, stream>>>(
                Qb, Kb, Vt, owh + (size_t)l * 4 * 224 * 64, x);
            k_gateup64<<<dim3(32, 28), 256, 0, stream>>>(
                x, guw + (size_t)l * 1792 * KP, ln2_w + (size_t)l * Dm, act);
            k_gemm_s2<<<dim3(32, 4, 2), 256, 0, stream>>>(
                act, dww + (size_t)l * 256 * 864, x, Dm, 864);
        }
        k_gemm_f<0, true><<<dim3(16, 250), 256, 0, stream>>>(
            x, lmw, nullptr, out, norm_w, Vv, KP);
    } else {
        // -------- legacy fp32 fallback --------
        float* ws = (float*)d_ws;
        size_t o2 = 0;
        float* x2    = ws + o2; o2 += (size_t)Tt * Dm;
        float* h2    = ws + o2; o2 += (size_t)Tt * Dm;
        float* qkv2  = ws + o2; o2 += (size_t)Tt * QKVW;
        float* aout2 = ws + o2; o2 += (size_t)Tt * Dm;
        float* act2  = ws + o2; o2 += (size_t)Tt * FFf;
        float* cosb2 = ws + o2; o2 += (size_t)Ss * HDd;
        float* sinb2 = ws + o2; o2 += (size_t)Ss * HDd;

        k_embed<<<Tt, 256, 0, stream>>>(ids, emb, x2);
        k_rope_tables<<<Ss, 64, 0, stream>>>(cosb2, sinb2);
        dim3 blk(TS, TS);
        for (int l = 0; l < NLAY; ++l) {
            k_rmsnorm<<<Tt, 64, 0, stream>>>(x2, ln1_w + (size_t)l * Dm, h2);
            k_gemm<<<dim3((QKVW + TS - 1) / TS, (Tt + TS - 1) / TS), blk, 0, stream>>>(
                h2, qkv_w + (size_t)l * QKVW * Dm, nullptr, qkv2, Tt, QKVW, Dm);
            k_rope<<<Tt, 256, 0, stream>>>(qkv2, cosb2, sinb2);
            k_attn<<<dim3(Ss, NHh, Bb), 256, 0, stream>>>(qkv2, aout2);
            k_gemm<<<dim3((Dm + TS - 1) / TS, (Tt + TS - 1) / TS), blk, 0, stream>>>(
                aout2, o_w + (size_t)l * Dm * Dm, x2, x2, Tt, Dm, Dm);
            k_rmsnorm<<<Tt, 64, 0, stream>>>(x2, ln2_w + (size_t)l * Dm, h2);
            k_gateup<<<dim3((FFf + TS - 1) / TS, (Tt + TS - 1) / TS), blk, 0, stream>>>(
                h2, gate_w + (size_t)l * FFf * Dm, up_w + (size_t)l * FFf * Dm, act2, Tt, FFf, Dm);
            k_gemm<<<dim3((Dm + TS - 1) / TS, (Tt + TS - 1) / TS), blk, 0, stream>>>(
                act2, down_w + (size_t)l * Dm * FFf, x2, x2, Tt, Dm, FFf);
        }
        k_rmsnorm<<<Tt, 64, 0, stream>>>(x2, norm_w, h2);
        k_gemm<<<dim3((Vv + TS - 1) / TS, (Tt + TS - 1) / TS), blk, 0, stream>>>(
            h2, lm_w, nullptr, out, Tt, Vv, Dm);
    }
}

// Round 15
// 852.464 us; speedup vs baseline: 1.7105x; 1.0192x over previous
//
#include <hip/hip_runtime.h>
#include <math.h>

#define Vv 32000
#define Dm 216
#define NLAY 11
#define NHh 4
#define HDd 54
#define FFf 864
#define Bb 2
#define Ss 1024
#define Tt (Bb*Ss)
#define EPSf 1e-5f
#define QKVW 648   // 3*Dm
#define KP 224     // K=216 padded to multiple of 32
#define HDP 64     // head dim padded
#define VTSZ (Ss*HDP)

typedef __attribute__((ext_vector_type(8))) short short8;
typedef __attribute__((ext_vector_type(8))) unsigned short ushort8;
typedef __attribute__((ext_vector_type(4))) float f32x4;

__device__ __forceinline__ unsigned short f2bf(float f) {
    unsigned int u = __float_as_uint(f);
    return (unsigned short)((u + 0x7fffu + ((u >> 16) & 1u)) >> 16);
}
__device__ __forceinline__ float bf2f(unsigned short u) {
    return __uint_as_float(((unsigned int)u) << 16);
}

// ================= setup: embed + tables + zero + weight convs (one launch) ========
__device__ void dev_convw(int relb, int nblk, const float* __restrict__ src,
                          unsigned short* __restrict__ dst,
                          int L, int N, int K, int Npad, int Kp, int rstride,
                          long dls, long doff) {
    size_t total = (size_t)L * Npad * Kp;
    for (size_t idx = (size_t)relb * 256 + threadIdx.x; idx < total;
         idx += (size_t)nblk * 256) {
        int k = (int)(idx % Kp);
        size_t rr = idx / Kp;
        int n = (int)(rr % Npad);
        int l = (int)(rr / Npad);
        float v = (n < N && k < K) ? src[((size_t)l * N + n) * K + k] : 0.f;
        dst[(size_t)l * dls + doff + (size_t)n * rstride + k] = f2bf(v);
    }
}

__device__ void dev_convqkv(int relb, int nblk, const float* __restrict__ src,
                            unsigned short* __restrict__ dst) {
    size_t total = (size_t)NLAY * 768 * KP;
    for (size_t idx = (size_t)relb * 256 + threadIdx.x; idx < total;
         idx += (size_t)nblk * 256) {
        int kk2 = (int)(idx % KP);
        size_t rr = idx / KP;
        int nr = (int)(rr % 768);
        int l = (int)(rr / 768);
        float v = 0.f;
        if (nr < 648 && kk2 < 216) {
            int srow;
            float sc = 1.f;
            if (nr < 432) {
                int which = nr >= 216;
                int cih = nr - which * 216;
                int head = cih / 54, dd = cih % 54;
                int j = dd >> 1, odd = dd & 1;
                srow = which * 216 + head * 54 + j + odd * 27;
                if (!which) sc = 0.13608276348795434f; // 54^-0.5 folded into q
            } else srow = nr;
            v = src[((size_t)l * QKVW + srow) * 216 + kk2] * sc;
        }
        dst[idx] = f2bf(v);
    }
}

// head-sliced o-weight: owh[l][h][n 224][k 64] = o_w[l][n][h*54+k] (zero padded)
__device__ void dev_convowh(int relb, int nblk, const float* __restrict__ src,
                            unsigned short* __restrict__ dst) {
    size_t total = (size_t)NLAY * 4 * 224 * 64;
    for (size_t idx = (size_t)relb * 256 + threadIdx.x; idx < total;
         idx += (size_t)nblk * 256) {
        int kk = (int)(idx & 63);
        size_t rr = idx >> 6;
        int n = (int)(rr % 224);
        size_t rh = rr / 224;
        int h = (int)(rh & 3);
        int l = (int)(rh >> 2);
        float v = (n < 216 && kk < 54)
            ? src[((size_t)l * 216 + n) * 216 + h * 54 + kk] : 0.f;
        dst[idx] = f2bf(v);
    }
}

__global__ void k_setup(const int* __restrict__ ids, const float* __restrict__ emb,
                        float* __restrict__ x,
                        float* __restrict__ cost, float* __restrict__ sint,
                        unsigned int* __restrict__ zp, size_t zwords,
                        const float* __restrict__ qkv_w, unsigned short* __restrict__ qkvw,
                        const float* __restrict__ o_w, unsigned short* __restrict__ owh,
                        const float* __restrict__ gate_w, const float* __restrict__ up_w,
                        unsigned short* __restrict__ guw,
                        const float* __restrict__ down_w, unsigned short* __restrict__ dww,
                        const float* __restrict__ lm_w, unsigned short* __restrict__ lmw)
{
    const int b = blockIdx.x;
    const int tid = threadIdx.x;
    if (b < 2048) {
        int id = ids[b];
        for (int d = tid; d < Dm; d += 256)
            x[(size_t)b * Dm + d] = emb[(size_t)id * Dm + d];
    } else if (b < 2176) {
        for (int idx = (b - 2048) * 256 + tid; idx < 1024 * 27; idx += 128 * 256) {
            int s = idx / 27, j = idx % 27;
            float inv = powf(10000.0f, -2.0f * (float)j / 54.0f);
            float f = (float)s * inv;
            cost[s * 27 + j] = cosf(f);
            sint[s * 27 + j] = sinf(f);
        }
    } else if (b < 2432) {
        for (size_t i = (size_t)(b - 2176) * 256 + tid; i < zwords; i += (size_t)256 * 256)
            zp[i] = 0;
    } else if (b < 2944) {
        dev_convqkv(b - 2432, 512, qkv_w, qkvw);
    } else if (b < 3200) {
        dev_convowh(b - 2944, 256, o_w, owh);
    } else if (b < 3712) {
        dev_convw(b - 3200, 512, gate_w, guw, NLAY, FFf, Dm, 896, KP, 2 * KP, 1792L * KP, 0);
    } else if (b < 4224) {
        dev_convw(b - 3712, 512, up_w, guw, NLAY, FFf, Dm, 896, KP, 2 * KP, 1792L * KP, KP);
    } else if (b < 4736) {
        dev_convw(b - 4224, 512, down_w, dww, NLAY, Dm, FFf, 256, 864, 864, 256L * 864, 0);
    } else {
        dev_convw(b - 4736, 1024, lm_w, lmw, 1, Vv, Dm, Vv, KP, KP, (long)Vv * KP, 0);
    }
}

// ================= shared phase helpers (proven rounds 6-14) =================
__device__ __forceinline__ void normpro(const float* __restrict__ x,
                                        const float* __restrict__ lnw, int m0,
                                        float* rsl, float* lnl, int tid) {
    __syncthreads();
    if (tid < 224) lnl[tid] = (tid < 216) ? lnw[tid] : 0.f;
    if (tid < 128) {
        int row = tid >> 1, half = tid & 1;
        const float* xr = x + (size_t)(m0 + row) * Dm + half * 108;
        float ss = 0.f;
        #pragma unroll
        for (int q = 0; q < 27; ++q) {
            float4 v = *(const float4*)(xr + q * 4);
            ss += v.x * v.x + v.y * v.y + v.z * v.z + v.w * v.w;
        }
        ss += __shfl_xor(ss, 1, 64);
        if (half == 0) rsl[row] = rsqrtf(ss / 216.f + EPSf);
    }
    __syncthreads();
}

__device__ __forceinline__ ushort8 normA(const float* __restrict__ x,
                                         const float* rsl, const float* lnl,
                                         int m0, int row, int base) {
    ushort8 o;
    if (base < 216) {
        const float* pp = x + (size_t)(m0 + row) * Dm + base;
        float r = rsl[row];
        float4 v0 = *(const float4*)pp;
        float4 v1 = *(const float4*)(pp + 4);
        o[0] = f2bf(v0.x * r * lnl[base + 0]);
        o[1] = f2bf(v0.y * r * lnl[base + 1]);
        o[2] = f2bf(v0.z * r * lnl[base + 2]);
        o[3] = f2bf(v0.w * r * lnl[base + 3]);
        o[4] = f2bf(v1.x * r * lnl[base + 4]);
        o[5] = f2bf(v1.y * r * lnl[base + 5]);
        o[6] = f2bf(v1.z * r * lnl[base + 6]);
        o[7] = f2bf(v1.w * r * lnl[base + 7]);
    } else {
        #pragma unroll
        for (int e = 0; e < 8; ++e) o[e] = 0;
    }
    return o;
}

// ================= qkv: 64x64 tiles, norm-fused A, rope/transpose epilogue =========
__global__ __launch_bounds__(256) void k_qkv64(
    const float* __restrict__ x, const unsigned short* __restrict__ W,
    const float* __restrict__ lnw,
    const float* __restrict__ cost, const float* __restrict__ sint,
    unsigned short* __restrict__ Qb, unsigned short* __restrict__ Kb,
    unsigned short* __restrict__ Vt)
{
    __shared__ __align__(16) unsigned char SM[17664];
    unsigned short* lA = (unsigned short*)SM;
    unsigned short* lB = (unsigned short*)(SM + 8192);
    float* rsl = (float*)(SM + 16384);
    float* lnl = (float*)(SM + 16640);
    const int tid = threadIdx.x;
    const int m0 = blockIdx.x * 64;
    const int n0 = blockIdx.y * 64;
    normpro(x, lnw, m0, rsl, lnl, tid);

    const int wid = tid >> 6, lane = tid & 63;
    const int wr = wid >> 1, wc = wid & 1;
    const int r = tid >> 2, kc = tid & 3;
    const int lo = (r >> 4) * 512 + (((kc << 4) | (r & 15)) << 3);

    ushort8 ra = normA(x, rsl, lnl, m0, r, kc * 8);
    ushort8 rb = *(const ushort8*)(W + (size_t)(n0 + r) * KP + kc * 8);
    *(ushort8*)&lA[lo] = ra;
    *(ushort8*)&lB[lo] = rb;
    __syncthreads();

    f32x4 acc[2][2] = {};
    int cur = 0;
    for (int step = 0; step < 7; ++step) {
        const bool more = step < 6;
        if (more) {
            const int k0 = (step + 1) << 5;
            ra = normA(x, rsl, lnl, m0, r, k0 + kc * 8);
            rb = *(const ushort8*)(W + (size_t)(n0 + r) * KP + k0 + kc * 8);
        }
        short8 af[2], bf2[2];
        #pragma unroll
        for (int f = 0; f < 2; ++f) {
            af[f] = *(const short8*)&lA[cur * 2048 + (wr * 2 + f) * 512 + lane * 8];
            bf2[f] = *(const short8*)&lB[cur * 2048 + (wc * 2 + f) * 512 + lane * 8];
        }
        #pragma unroll
        for (int fm = 0; fm < 2; ++fm)
            #pragma unroll
            for (int fn = 0; fn < 2; ++fn)
                acc[fm][fn] = __builtin_amdgcn_mfma_f32_16x16x32_bf16(af[fm], bf2[fn], acc[fm][fn], 0, 0, 0);
        if (more) {
            const int nxt = cur ^ 1;
            *(ushort8*)&lA[nxt * 2048 + lo] = ra;
            *(ushort8*)&lB[nxt * 2048 + lo] = rb;
            __syncthreads();
            cur = nxt;
        }
    }

    const int lc16 = lane & 15, lg = lane >> 4;
    #pragma unroll
    for (int fm = 0; fm < 2; ++fm) {
        const int mrow = m0 + wr * 32 + fm * 16 + lg * 4;
        const int b = mrow >> 10;
        const int st0 = mrow & 1023;
        #pragma unroll
        for (int fn = 0; fn < 2; ++fn) {
            const int ncol = n0 + wc * 32 + fn * 16 + lc16;
            float v0 = acc[fm][fn][0], v1 = acc[fm][fn][1];
            float v2 = acc[fm][fn][2], v3 = acc[fm][fn][3];
            float p0 = __shfl_xor(v0, 1, 64);
            float p1 = __shfl_xor(v1, 1, 64);
            float p2 = __shfl_xor(v2, 1, 64);
            float p3 = __shfl_xor(v3, 1, 64);
            if (ncol < 432) {
                int which = ncol >= 216;
                int cih = ncol - which * 216;
                int head = cih / 54, dd = cih % 54;
                int j = dd >> 1;
                bool odd = dd & 1;
                unsigned short* dst = (which ? Kb : Qb) +
                    ((size_t)(b * NHh + head) * Ss + st0) * HDP + dd;
                float vv[4] = {v0, v1, v2, v3};
                float pp[4] = {p0, p1, p2, p3};
                #pragma unroll
                for (int i = 0; i < 4; ++i) {
                    float c = cost[(st0 + i) * 27 + j];
                    float sn = sint[(st0 + i) * 27 + j];
                    float o = odd ? (vv[i] * c + pp[i] * sn) : (vv[i] * c - pp[i] * sn);
                    dst[(size_t)i * HDP] = f2bf(o);
                }
            } else if (ncol < 648) {
                int d = ncol - 432;
                int head = d / 54, dd = d % 54;
                ushort4 pk;
                pk.x = f2bf(v0); pk.y = f2bf(v1); pk.z = f2bf(v2); pk.w = f2bf(v3);
                *(ushort4*)(Vt + (size_t)(b * NHh + head) * VTSZ + (size_t)dd * Ss + st0) = pk;
            }
        }
    }
}

// ================= gate/up: 64x64 tiles, norm-fused A, silu epilogue =========
__global__ __launch_bounds__(256) void k_gateup64(
    const float* __restrict__ x, const unsigned short* __restrict__ W,
    const float* __restrict__ lnw, unsigned short* __restrict__ act)
{
    __shared__ __align__(16) unsigned char SM[17664];
    unsigned short* lA = (unsigned short*)SM;
    unsigned short* lB = (unsigned short*)(SM + 8192);
    float* rsl = (float*)(SM + 16384);
    float* lnl = (float*)(SM + 16640);
    const int tid = threadIdx.x;
    const int m0 = blockIdx.x * 64;
    const int n0 = blockIdx.y * 64;
    normpro(x, lnw, m0, rsl, lnl, tid);

    const int wid = tid >> 6, lane = tid & 63;
    const int wr = wid >> 1, wc = wid & 1;
    const int r = tid >> 2, kc = tid & 3;
    const int lo = (r >> 4) * 512 + (((kc << 4) | (r & 15)) << 3);

    ushort8 ra = normA(x, rsl, lnl, m0, r, kc * 8);
    ushort8 rb = *(const ushort8*)(W + (size_t)(n0 + r) * KP + kc * 8);
    *(ushort8*)&lA[lo] = ra;
    *(ushort8*)&lB[lo] = rb;
    __syncthreads();

    f32x4 acc[2][2] = {};
    int cur = 0;
    for (int step = 0; step < 7; ++step) {
        const bool more = step < 6;
        if (more) {
            const int k0 = (step + 1) << 5;
            ra = normA(x, rsl, lnl, m0, r, k0 + kc * 8);
            rb = *(const ushort8*)(W + (size_t)(n0 + r) * KP + k0 + kc * 8);
        }
        short8 af[2], bf2[2];
        #pragma unroll
        for (int f = 0; f < 2; ++f) {
            af[f] = *(const short8*)&lA[cur * 2048 + (wr * 2 + f) * 512 + lane * 8];
            bf2[f] = *(const short8*)&lB[cur * 2048 + (wc * 2 + f) * 512 + lane * 8];
        }
        #pragma unroll
        for (int fm = 0; fm < 2; ++fm)
            #pragma unroll
            for (int fn = 0; fn < 2; ++fn)
                acc[fm][fn] = __builtin_amdgcn_mfma_f32_16x16x32_bf16(af[fm], bf2[fn], acc[fm][fn], 0, 0, 0);
        if (more) {
            const int nxt = cur ^ 1;
            *(ushort8*)&lA[nxt * 2048 + lo] = ra;
            *(ushort8*)&lB[nxt * 2048 + lo] = rb;
            __syncthreads();
            cur = nxt;
        }
    }

    const int lc16 = lane & 15, lg = lane >> 4;
    #pragma unroll
    for (int fm = 0; fm < 2; ++fm) {
        const int mrow = m0 + wr * 32 + fm * 16 + lg * 4;
        #pragma unroll
        for (int fn = 0; fn < 2; ++fn) {
            const int ncol = n0 + wc * 32 + fn * 16 + lc16;
            #pragma unroll
            for (int i = 0; i < 4; ++i) {
                float v = acc[fm][fn][i];
                float p = __shfl_xor(v, 1, 64);
                if ((lc16 & 1) == 0 && ncol < 1728) {
                    float y = v / (1.f + __expf(-v)) * p;
                    act[(size_t)(mrow + i) * 864 + (ncol >> 1)] = f2bf(y);
                }
            }
        }
    }
}

// ====== down GEMM: 64x64 tile, split-K=2 (grid z), atomicAdd into x ======
__global__ __launch_bounds__(256) void k_gemm_s2(
    const unsigned short* __restrict__ A, const unsigned short* __restrict__ W,
    float* __restrict__ xio, int N, int Kp)
{
    __shared__ __align__(16) unsigned short lA[2][2048];
    __shared__ __align__(16) unsigned short lB[2][2048];
    const int tid = threadIdx.x;
    const int m0 = blockIdx.x * 64, n0 = blockIdx.y * 64;
    const int kz = blockIdx.z;
    const int nsteps_tot = Kp >> 5;                 // 27 for K=864
    const int s0 = kz ? (nsteps_tot / 2 + 1) : 0;   // kz0: [0,14), kz1: [14,27)
    const int s1 = kz ? nsteps_tot : (nsteps_tot / 2 + 1);
    const int nsteps = s1 - s0;
    const int wid = tid >> 6, lane = tid & 63;
    const int wr = wid >> 1, wc = wid & 1;
    const int r = tid >> 2, kc = tid & 3;
    const int lo = (r >> 4) * 512 + (((kc << 4) | (r & 15)) << 3);

    ushort8 ra = *(const ushort8*)(A + (size_t)(m0 + r) * Kp + s0 * 32 + kc * 8);
    ushort8 rb = *(const ushort8*)(W + (size_t)(n0 + r) * Kp + s0 * 32 + kc * 8);
    *(ushort8*)&lA[0][lo] = ra;
    *(ushort8*)&lB[0][lo] = rb;
    __syncthreads();

    f32x4 acc[2][2] = {};
    int cur = 0;
    for (int step = 0; step < nsteps; ++step) {
        const bool more = (step + 1) < nsteps;
        if (more) {
            const int k0 = (s0 + step + 1) << 5;
            ra = *(const ushort8*)(A + (size_t)(m0 + r) * Kp + k0 + kc * 8);
            rb = *(const ushort8*)(W + (size_t)(n0 + r) * Kp + k0 + kc * 8);
        }
        short8 af[2], bf2[2];
        #pragma unroll
        for (int f = 0; f < 2; ++f) {
            af[f] = *(const short8*)&lA[cur][(wr * 2 + f) * 512 + lane * 8];
            bf2[f] = *(const short8*)&lB[cur][(wc * 2 + f) * 512 + lane * 8];
        }
        #pragma unroll
        for (int fm = 0; fm < 2; ++fm)
            #pragma unroll
            for (int fn = 0; fn < 2; ++fn)
                acc[fm][fn] = __builtin_amdgcn_mfma_f32_16x16x32_bf16(af[fm], bf2[fn], acc[fm][fn], 0, 0, 0);
        if (more) {
            const int nxt = cur ^ 1;
            *(ushort8*)&lA[nxt][lo] = ra;
            *(ushort8*)&lB[nxt][lo] = rb;
            __syncthreads();
            cur = nxt;
        }
    }

    #pragma unroll
    for (int fm = 0; fm < 2; ++fm) {
        const int mrow = m0 + wr * 32 + fm * 16 + (lane >> 4) * 4;
        #pragma unroll
        for (int fn = 0; fn < 2; ++fn) {
            const int ncol = n0 + wc * 32 + fn * 16 + (lane & 15);
            if (ncol < N) {
                #pragma unroll
                for (int i = 0; i < 4; ++i) {
                    const size_t oi = (size_t)(mrow + i) * N + ncol;
                    atomicAdd(&xio[oi], acc[fm][fn][i]);
                }
            }
        }
    }
}

// ===== attention (16 q-rows, 4-wave kv-split, wave-private staging) + fused o-proj
// Deepest-first block ordering: qu = 63 - blockIdx.x (LPT scheduling, tail shave) =====
__global__ __launch_bounds__(256) void k_attn_o16(
    const unsigned short* __restrict__ Qb, const unsigned short* __restrict__ Kb,
    const unsigned short* __restrict__ Vt, const unsigned short* __restrict__ owh_l,
    float* __restrict__ x)
{
    __shared__ __align__(16) unsigned char SM[38912];
    const int tid = threadIdx.x;
    const int qu = 63 - blockIdx.x, h = blockIdx.y, b = blockIdx.z;
    const int bh = b * NHh + h;
    const int q0w = qu * 16;
    const int w = tid >> 6, lane = tid & 63;
    const int lc = lane & 15, lg = lane >> 4;

    unsigned short* Klw = (unsigned short*)(SM + w * 4096);          // 32k x 64d frag-order
    unsigned short* Vlw = (unsigned short*)(SM + 16384 + w * 4096);  // 64d x 32k frag-order
    unsigned short* Plw = (unsigned short*)(SM + 32768 + w * 1024);  // 16q x 32k A-frag
    unsigned short* Ol  = (unsigned short*)(SM + 36864);             // 16q x 64k A-frag

    const unsigned short* Qp = Qb + (size_t)bh * VTSZ;
    const unsigned short* Kpp = Kb + (size_t)bh * VTSZ;
    const unsigned short* Vp = Vt + (size_t)bh * VTSZ;
    const unsigned short* owh_h = owh_l + (size_t)h * 224 * 64;

    short8 qa[2];
    #pragma unroll
    for (int half = 0; half < 2; ++half)
        qa[half] = *(const short8*)(Qp + (size_t)(q0w + lc) * HDP + lg * 8 + half * 32);

    f32x4 o4[4] = {};
    float mreg[4] = {-3e38f, -3e38f, -3e38f, -3e38f};
    float lreg[4] = {0.f, 0.f, 0.f, 0.f};

    const int nt = (q0w + 15) / 32 + 1;
    for (int t = w; t < nt; t += 4) {
        const int kv0 = t * 32;
        for (int c = lane; c < 512; c += 64) {
            if (c < 256) {
                int sub = c >> 6;
                int kgrp = sub >> 1, dhalf = sub & 1;
                int dchunk = (c >> 4) & 3, krow = c & 15;
                *(ushort8*)&Klw[sub * 512 + (c & 63) * 8] =
                    *(const ushort8*)(Kpp + (size_t)(kv0 + kgrp * 16 + krow) * HDP + dhalf * 32 + dchunk * 8);
            } else {
                int c2 = c - 256;
                int dgrp = c2 >> 6;
                int kchunk = (c2 >> 4) & 3, dcol = c2 & 15;
                *(ushort8*)&Vlw[dgrp * 512 + (c2 & 63) * 8] =
                    *(const ushort8*)(Vp + (size_t)(dgrp * 16 + dcol) * Ss + kv0 + kchunk * 8);
            }
        }
        f32x4 s4[2] = {};
        #pragma unroll
        for (int dhalf = 0; dhalf < 2; ++dhalf) {
            #pragma unroll
            for (int kgrp = 0; kgrp < 2; ++kgrp) {
                short8 kf = *(const short8*)&Klw[(kgrp * 2 + dhalf) * 512 + lane * 8];
                s4[kgrp] = __builtin_amdgcn_mfma_f32_16x16x32_bf16(qa[dhalf], kf, s4[kgrp], 0, 0, 0);
            }
        }
        if (kv0 + 31 > q0w) {
            #pragma unroll
            for (int kgrp = 0; kgrp < 2; ++kgrp) {
                int kg = kv0 + kgrp * 16 + lc;
                #pragma unroll
                for (int rr = 0; rr < 4; ++rr) {
                    int qg = q0w + lg * 4 + rr;
                    if (kg > qg) s4[kgrp][rr] = -3e38f;
                }
            }
        }
        #pragma unroll
        for (int rr = 0; rr < 4; ++rr) {
            float rm = fmaxf(s4[0][rr], s4[1][rr]);
            #pragma unroll
            for (int msk = 1; msk < 16; msk <<= 1)
                rm = fmaxf(rm, __shfl_xor(rm, msk, 64));
            float mn = fmaxf(mreg[rr], rm);
            float esc = __expf(mreg[rr] - mn);
            mreg[rr] = mn;
            float e0 = __expf(s4[0][rr] - mn);
            float e1 = __expf(s4[1][rr] - mn);
            float rs = e0 + e1;
            #pragma unroll
            for (int msk = 1; msk < 16; msk <<= 1)
                rs += __shfl_xor(rs, msk, 64);
            lreg[rr] = lreg[rr] * esc + rs;
            #pragma unroll
            for (int db = 0; db < 4; ++db) o4[db][rr] *= esc;
            int q = lg * 4 + rr;
            Plw[(((lc >> 3)) * 16 + q) * 8 + (lc & 7)] = f2bf(e0);
            Plw[((2 + (lc >> 3)) * 16 + q) * 8 + (lc & 7)] = f2bf(e1);
        }
        short8 pa = *(const short8*)&Plw[(lg * 16 + lc) * 8];
        #pragma unroll
        for (int db = 0; db < 4; ++db) {
            short8 vf = *(const short8*)&Vlw[db * 512 + lane * 8];
            o4[db] = __builtin_amdgcn_mfma_f32_16x16x32_bf16(pa, vf, o4[db], 0, 0, 0);
        }
    }

    __syncthreads();
    float* mg = (float*)SM;
    const int slot = (w * 64 + lane) * 25;
    #pragma unroll
    for (int rr = 0; rr < 4; ++rr) { mg[slot + rr] = mreg[rr]; mg[slot + 4 + rr] = lreg[rr]; }
    #pragma unroll
    for (int db = 0; db < 4; ++db)
        #pragma unroll
        for (int rr = 0; rr < 4; ++rr) mg[slot + 8 + db * 4 + rr] = o4[db][rr];
    __syncthreads();
    if (w == 0) {
        #pragma unroll
        for (int rr = 0; rr < 4; ++rr) {
            float m = mreg[rr];
            #pragma unroll
            for (int ww = 1; ww < 4; ++ww)
                m = fmaxf(m, mg[(ww * 64 + lane) * 25 + rr]);
            float eself = __expf(mreg[rr] - m);
            float l = lreg[rr] * eself;
            float oc[4];
            #pragma unroll
            for (int db = 0; db < 4; ++db) oc[db] = o4[db][rr] * eself;
            #pragma unroll
            for (int ww = 1; ww < 4; ++ww) {
                int sl = (ww * 64 + lane) * 25;
                float e = __expf(mg[sl + rr] - m);
                l += mg[sl + 4 + rr] * e;
                #pragma unroll
                for (int db = 0; db < 4; ++db) oc[db] += mg[sl + 8 + db * 4 + rr] * e;
            }
            float inv = 1.f / l;
            int q = lg * 4 + rr;
            #pragma unroll
            for (int db = 0; db < 4; ++db) {
                int kchunk = db * 2 + (lc >> 3);
                Ol[(kchunk * 16 + q) * 8 + (lc & 7)] = f2bf(oc[db] * inv);
            }
        }
    }
    __syncthreads();

    f32x4 oacc[4] = {};
    #pragma unroll
    for (int ks = 0; ks < 2; ++ks) {
        short8 afr = *(const short8*)&Ol[ks * 512 + lane * 8];
        #pragma unroll
        for (int gi = 0; gi < 4; ++gi) {
            int g = gi * 4 + w;
            if (g < 14) {
                int n = g * 16 + lc;
                short8 bfr = *(const short8*)(owh_h + (size_t)n * 64 + ks * 32 + lg * 8);
                oacc[gi] = __builtin_amdgcn_mfma_f32_16x16x32_bf16(afr, bfr, oacc[gi], 0, 0, 0);
            }
        }
    }
    #pragma unroll
    for (int gi = 0; gi < 4; ++gi) {
        int g = gi * 4 + w;
        if (g < 14) {
            int col = g * 16 + lc;
            if (col < 216) {
                #pragma unroll
                for (int i = 0; i < 4; ++i) {
                    int row = b * Ss + q0w + lg * 4 + i;
                    atomicAdd(&x[(size_t)row * Dm + col], oacc[gi][i]);
                }
            }
        }
    }
}

// ================= fused MFMA GEMM (128x128) — LM head w/ norm-A ==========
template<int OUTM, bool NORMA>
__global__ __launch_bounds__(256, 2) void k_gemm_f(
    const void* __restrict__ Av, const unsigned short* __restrict__ W,
    const float* __restrict__ res, void* __restrict__ outv,
    const float* __restrict__ lnw, int N, int Kp)
{
    __shared__ __align__(16) unsigned short lds[2][2][4096];
    __shared__ float rsl[128];
    __shared__ float lnl[224];
    const int tid = threadIdx.x;
    const int m0 = blockIdx.x * 128;
    const int n0 = blockIdx.y * 128;
    const int wid = tid >> 6, lane = tid & 63;
    const int wr = wid >> 1, wc = wid & 1;
    const int nsteps = Kp >> 5;

    if constexpr (NORMA) {
        const float* Af = (const float*)Av;
        if (tid < 224) lnl[tid] = (tid < 216) ? lnw[tid] : 0.f;
        int row = tid >> 1, half = tid & 1;
        const float* xr = Af + (size_t)(m0 + row) * 216 + half * 108;
        float ss = 0.f;
        #pragma unroll
        for (int q = 0; q < 27; ++q) {
            float4 v = *(const float4*)(xr + q * 4);
            ss += v.x * v.x + v.y * v.y + v.z * v.z + v.w * v.w;
        }
        ss += __shfl_xor(ss, 1, 64);
        if (half == 0) rsl[row] = rsqrtf(ss / 216.f + EPSf);
        __syncthreads();
    }

    const int i0 = tid, i1 = tid + 256;
    const int rA0 = i0 >> 2, cA0 = i0 & 3;
    const int rA1 = i1 >> 2, cA1 = i1 & 3;
    const int lo0 = (rA0 >> 4) * 512 + (((cA0 << 4) | (rA0 & 15)) << 3);
    const int lo1 = (rA1 >> 4) * 512 + (((cA1 << 4) | (rA1 & 15)) << 3);

    auto loadA = [&](int row, int base) -> ushort8 {
        ushort8 o;
        if constexpr (NORMA) {
            if (base < 216) {
                const float* p = (const float*)Av + (size_t)(m0 + row) * 216 + base;
                float r = rsl[row];
                float4 v0 = *(const float4*)p;
                float4 v1 = *(const float4*)(p + 4);
                o[0] = f2bf(v0.x * r * lnl[base + 0]);
                o[1] = f2bf(v0.y * r * lnl[base + 1]);
                o[2] = f2bf(v0.z * r * lnl[base + 2]);
                o[3] = f2bf(v0.w * r * lnl[base + 3]);
                o[4] = f2bf(v1.x * r * lnl[base + 4]);
                o[5] = f2bf(v1.y * r * lnl[base + 5]);
                o[6] = f2bf(v1.z * r * lnl[base + 6]);
                o[7] = f2bf(v1.w * r * lnl[base + 7]);
            } else {
                #pragma unroll
                for (int e = 0; e < 8; ++e) o[e] = 0;
            }
        } else {
            o = *(const ushort8*)((const unsigned short*)Av + (size_t)(m0 + row) * Kp + base);
        }
        return o;
    };

    ushort8 ra0, ra1, rb0, rb1;
    ra0 = loadA(rA0, cA0 * 8);
    ra1 = loadA(rA1, cA1 * 8);
    rb0 = *(const ushort8*)(W + (size_t)(n0 + rA0) * Kp + cA0 * 8);
    rb1 = *(const ushort8*)(W + (size_t)(n0 + rA1) * Kp + cA1 * 8);
    *(ushort8*)&lds[0][0][lo0] = ra0;
    *(ushort8*)&lds[0][0][lo1] = ra1;
    *(ushort8*)&lds[0][1][lo0] = rb0;
    *(ushort8*)&lds[0][1][lo1] = rb1;
    __syncthreads();

    f32x4 acc[4][4] = {};
    int cur = 0;
    for (int step = 0; step < nsteps; ++step) {
        const bool more = (step + 1) < nsteps;
        if (more) {
            const int k0 = (step + 1) << 5;
            ra0 = loadA(rA0, k0 + cA0 * 8);
            ra1 = loadA(rA1, k0 + cA1 * 8);
            rb0 = *(const ushort8*)(W + (size_t)(n0 + rA0) * Kp + k0 + cA0 * 8);
            rb1 = *(const ushort8*)(W + (size_t)(n0 + rA1) * Kp + k0 + cA1 * 8);
        }
        short8 af[4], bf[4];
        #pragma unroll
        for (int f = 0; f < 4; ++f) {
            af[f] = *(const short8*)&lds[cur][0][(wr * 4 + f) * 512 + lane * 8];
            bf[f] = *(const short8*)&lds[cur][1][(wc * 4 + f) * 512 + lane * 8];
        }
        #pragma unroll
        for (int fm = 0; fm < 4; ++fm)
            #pragma unroll
            for (int fn = 0; fn < 4; ++fn)
                acc[fm][fn] = __builtin_amdgcn_mfma_f32_16x16x32_bf16(af[fm], bf[fn], acc[fm][fn], 0, 0, 0);
        if (more) {
            const int nxt = cur ^ 1;
            *(ushort8*)&lds[nxt][0][lo0] = ra0;
            *(ushort8*)&lds[nxt][0][lo1] = ra1;
            *(ushort8*)&lds[nxt][1][lo0] = rb0;
            *(ushort8*)&lds[nxt][1][lo1] = rb1;
            __syncthreads();
            cur = nxt;
        }
    }

    const int lc16 = lane & 15;
    #pragma unroll
    for (int fm = 0; fm < 4; ++fm) {
        const int mrow = m0 + wr * 64 + fm * 16 + (lane >> 4) * 4;
        #pragma unroll
        for (int fn = 0; fn < 4; ++fn) {
            const int ncol = n0 + wc * 64 + fn * 16 + lc16;
            if (ncol < N) {
                #pragma unroll
                for (int i = 0; i < 4; ++i) {
                    const size_t oi = (size_t)(mrow + i) * N + ncol;
                    float v = acc[fm][fn][i];
                    if (res) v += res[oi];
                    ((float*)outv)[oi] = v;
                }
            }
        }
    }
}

// ================= legacy fp32 fallback kernels =================
__global__ void k_embed(const int* __restrict__ ids, const float* __restrict__ emb,
                        float* __restrict__ x) {
    int t = blockIdx.x;
    int id = ids[t];
    for (int d = threadIdx.x; d < Dm; d += blockDim.x)
        x[(size_t)t * Dm + d] = emb[(size_t)id * Dm + d];
}

__global__ void k_rope_tables(float* __restrict__ cosb, float* __restrict__ sinb) {
    int s = blockIdx.x;
    for (int d = threadIdx.x; d < HDd; d += blockDim.x) {
        int j = d % (HDd / 2);
        float inv = powf(10000.0f, -2.0f * (float)j / (float)HDd);
        float f = (float)s * inv;
        cosb[s * HDd + d] = cosf(f);
        sinb[s * HDd + d] = sinf(f);
    }
}

__global__ void k_rmsnorm(const float* __restrict__ x, const float* __restrict__ w,
                          float* __restrict__ h) {
    int t = blockIdx.x;
    const float* xr = x + (size_t)t * Dm;
    float ss = 0.f;
    for (int d = threadIdx.x; d < Dm; d += 64) { float v = xr[d]; ss += v * v; }
    for (int o = 32; o; o >>= 1) ss += __shfl_down(ss, o, 64);
    float r = __shfl(ss, 0, 64);
    r = rsqrtf(r / (float)Dm + EPSf);
    for (int d = threadIdx.x; d < Dm; d += 64)
        h[(size_t)t * Dm + d] = xr[d] * r * w[d];
}

#define TS 16
__global__ void k_gemm(const float* __restrict__ A, const float* __restrict__ W,
                       const float* __restrict__ res, float* __restrict__ out,
                       int M, int N, int K) {
    __shared__ float As[TS][TS + 1];
    __shared__ float Wsm[TS][TS + 1];
    const int tx = threadIdx.x, ty = threadIdx.y;
    const int m = blockIdx.y * TS + ty;
    const int n = blockIdx.x * TS + tx;
    float acc = 0.f;
    for (int k0 = 0; k0 < K; k0 += TS) {
        int ka = k0 + tx;
        As[ty][tx] = (m < M && ka < K) ? A[(size_t)m * K + ka] : 0.f;
        int nw = blockIdx.x * TS + ty;
        Wsm[ty][tx] = (nw < N && ka < K) ? W[(size_t)nw * K + ka] : 0.f;
        __syncthreads();
        #pragma unroll
        for (int kk = 0; kk < TS; ++kk) acc += As[ty][kk] * Wsm[tx][kk];
        __syncthreads();
    }
    if (m < M && n < N) {
        float r = res ? res[(size_t)m * N + n] : 0.f;
        out[(size_t)m * N + n] = r + acc;
    }
}

__global__ void k_gateup(const float* __restrict__ A, const float* __restrict__ Wg,
                         const float* __restrict__ Wu, float* __restrict__ act,
                         int M, int N, int K) {
    __shared__ float As[TS][TS + 1];
    __shared__ float Gs[TS][TS + 1];
    __shared__ float Us[TS][TS + 1];
    const int tx = threadIdx.x, ty = threadIdx.y;
    const int m = blockIdx.y * TS + ty;
    const int n = blockIdx.x * TS + tx;
    float ag = 0.f, au = 0.f;
    for (int k0 = 0; k0 < K; k0 += TS) {
        int ka = k0 + tx;
        As[ty][tx] = (m < M && ka < K) ? A[(size_t)m * K + ka] : 0.f;
        int nw = blockIdx.x * TS + ty;
        Gs[ty][tx] = (nw < N && ka < K) ? Wg[(size_t)nw * K + ka] : 0.f;
        Us[ty][tx] = (nw < N && ka < K) ? Wu[(size_t)nw * K + ka] : 0.f;
        __syncthreads();
        #pragma unroll
        for (int kk = 0; kk < TS; ++kk) {
            ag += As[ty][kk] * Gs[tx][kk];
            au += As[ty][kk] * Us[tx][kk];
        }
        __syncthreads();
    }
    if (m < M && n < N) {
        float sg = ag / (1.f + expf(-ag));
        act[(size_t)m * N + n] = sg * au;
    }
}

__global__ void k_rope(float* __restrict__ qkv, const float* __restrict__ cosb,
                       const float* __restrict__ sinb) {
    const int t = blockIdx.x;
    const int s = t % Ss;
    float* base = qkv + (size_t)t * QKVW;
    const int HALF = HDd / 2;
    int i = threadIdx.x;
    if (i < 2 * NHh * HALF) {
        int which = i / (NHh * HALF);
        int rem = i % (NHh * HALF);
        int hh = rem / HALF;
        int d = rem % HALF;
        float* ptr = base + which * Dm + hh * HDd;
        float x1 = ptr[d], x2 = ptr[d + HALF];
        float c1 = cosb[s * HDd + d], s1 = sinb[s * HDd + d];
        float c2 = cosb[s * HDd + d + HALF], s2 = sinb[s * HDd + d + HALF];
        ptr[d]        = x1 * c1 - x2 * s1;
        ptr[d + HALF] = x2 * c2 + x1 * s2;
    }
}

__global__ void k_attn(const float* __restrict__ qkv, float* __restrict__ aout) {
    const int q = blockIdx.x, h = blockIdx.y, b = blockIdx.z;
    const int tid = threadIdx.x;
    __shared__ float p[Ss];
    __shared__ float qv[HDd];
    __shared__ float rmax[4], rsum[4];
    const size_t base = (size_t)b * Ss * QKVW;
    const float* qrow = qkv + base + (size_t)q * QKVW + h * HDd;
    if (tid < HDd) qv[tid] = qrow[tid];
    __syncthreads();
    const int nk = q + 1;
    const float scale = 0.13608276348795434f;
    float lmax = -3.0e38f;
    for (int k = tid; k < nk; k += 256) {
        const float* krow = qkv + base + (size_t)k * QKVW + Dm + h * HDd;
        float acc = 0.f;
        #pragma unroll
        for (int d = 0; d < HDd; ++d) acc += qv[d] * krow[d];
        acc *= scale;
        p[k] = acc;
        lmax = fmaxf(lmax, acc);
    }
    for (int o = 32; o; o >>= 1) lmax = fmaxf(lmax, __shfl_down(lmax, o, 64));
    if ((tid & 63) == 0) rmax[tid >> 6] = lmax;
    __syncthreads();
    const float m = fmaxf(fmaxf(rmax[0], rmax[1]), fmaxf(rmax[2], rmax[3]));
    float lsum = 0.f;
    for (int k = tid; k < nk; k += 256) {
        float e = expf(p[k] - m);
        p[k] = e;
        lsum += e;
    }
    for (int o = 32; o; o >>= 1) lsum += __shfl_down(lsum, o, 64);
    if ((tid & 63) == 0) rsum[tid >> 6] = lsum;
    __syncthreads();
    const float inv = 1.f / (rsum[0] + rsum[1] + rsum[2] + rsum[3]);
    for (int d = tid; d < HDd; d += 256) {
        const float* vcol = qkv + base + 2 * Dm + h * HDd + d;
        float acc = 0.f;
        for (int k = 0; k < nk; ++k) acc += p[k] * vcol[(size_t)k * QKVW];
        aout[(size_t)(b * Ss + q) * Dm + h * HDd + d] = acc * inv;
    }
}

// =====================================================================
extern "C" void kernel_launch(void* const* d_in, const int* in_sizes, int n_in,
                              void* d_out, int out_size, void* d_ws, size_t ws_size,
                              hipStream_t stream) {
    const int*   ids    = (const int*)d_in[0];
    const float* emb    = (const float*)d_in[1];
    const float* ln1_w  = (const float*)d_in[2];
    const float* qkv_w  = (const float*)d_in[3];
    const float* o_w    = (const float*)d_in[4];
    const float* ln2_w  = (const float*)d_in[5];
    const float* gate_w = (const float*)d_in[6];
    const float* up_w   = (const float*)d_in[7];
    const float* down_w = (const float*)d_in[8];
    const float* norm_w = (const float*)d_in[9];
    const float* lm_w   = (const float*)d_in[10];
    float* out = (float*)d_out;

    char* base = (char*)d_ws;
    size_t off = 0;
    auto carve = [&](size_t bytes) -> char* {
        char* p = base + off;
        off += (bytes + 255) & ~(size_t)255;
        return p;
    };

    // fp32 buffers
    float* x     = (float*)carve((size_t)Tt * Dm * 4);
    float* cos27 = (float*)carve((size_t)Ss * 27 * 4);
    float* sin27 = (float*)carve((size_t)Ss * 27 * 4);
    // bf16 buffers (Qb..Vt contiguous, pads zeroed every call by setup)
    unsigned short* Qb   = (unsigned short*)carve((size_t)Bb * NHh * VTSZ * 2);
    unsigned short* Kb   = (unsigned short*)carve((size_t)Bb * NHh * VTSZ * 2);
    unsigned short* Vt   = (unsigned short*)carve((size_t)Bb * NHh * VTSZ * 2);
    char* zend = base + off;
    unsigned short* act  = (unsigned short*)carve((size_t)Tt * FFf * 2);
    unsigned short* qkvw = (unsigned short*)carve((size_t)NLAY * 768 * KP * 2);
    unsigned short* owh  = (unsigned short*)carve((size_t)NLAY * 4 * 224 * 64 * 2);
    unsigned short* guw  = (unsigned short*)carve((size_t)NLAY * 1792 * KP * 2);
    unsigned short* dww  = (unsigned short*)carve((size_t)NLAY * 256 * 864 * 2);
    unsigned short* lmw  = (unsigned short*)carve((size_t)Vv * KP * 2);
    size_t need = off;

    if (ws_size >= need) {
        size_t zwords = (size_t)(zend - (char*)Qb) / 4;
        k_setup<<<5760, 256, 0, stream>>>(ids, emb, x, cos27, sin27,
            (unsigned int*)Qb, zwords, qkv_w, qkvw, o_w, owh,
            gate_w, up_w, guw, down_w, dww, lm_w, lmw);

        for (int l = 0; l < NLAY; ++l) {
            k_qkv64<<<dim3(32, 12), 256, 0, stream>>>(
                x, qkvw + (size_t)l * 768 * KP, ln1_w + (size_t)l * Dm,
                cos27, sin27, Qb, Kb, Vt);
            k_attn_o16<<<dim3(64, NHh, Bb), 256, 0, stream>>>(
                Qb, Kb, Vt, owh + (size_t)l * 4 * 224 * 64, x);
            k_gateup64<<<dim3(32, 28), 256, 0, stream>>>(
                x, guw + (size_t)l * 1792 * KP, ln2_w + (size_t)l * Dm, act);
            k_gemm_s2<<<dim3(32, 4, 2), 256, 0, stream>>>(
                act, dww + (size_t)l * 256 * 864, x, Dm, 864);
        }
        k_gemm_f<0, true><<<dim3(16, 250), 256, 0, stream>>>(
            x, lmw, nullptr, out, norm_w, Vv, KP);
    } else {
        // -------- legacy fp32 fallback --------
        float* ws = (float*)d_ws;
        size_t o2 = 0;
        float* x2    = ws + o2; o2 += (size_t)Tt * Dm;
        float* h2    = ws + o2; o2 += (size_t)Tt * Dm;
        float* qkv2  = ws + o2; o2 += (size_t)Tt * QKVW;
        float* aout2 = ws + o2; o2 += (size_t)Tt * Dm;
        float* act2  = ws + o2; o2 += (size_t)Tt * FFf;
        float* cosb2 = ws + o2; o2 += (size_t)Ss * HDd;
        float* sinb2 = ws + o2; o2 += (size_t)Ss * HDd;

        k_embed<<<Tt, 256, 0, stream>>>(ids, emb, x2);
        k_rope_tables<<<Ss, 64, 0, stream>>>(cosb2, sinb2);
        dim3 blk(TS, TS);
        for (int l = 0; l < NLAY; ++l) {
            k_rmsnorm<<<Tt, 64, 0, stream>>>(x2, ln1_w + (size_t)l * Dm, h2);
            k_gemm<<<dim3((QKVW + TS - 1) / TS, (Tt + TS - 1) / TS), blk, 0, stream>>>(
                h2, qkv_w + (size_t)l * QKVW * Dm, nullptr, qkv2, Tt, QKVW, Dm);
            k_rope<<<Tt, 256, 0, stream>>>(qkv2, cosb2, sinb2);
            k_attn<<<dim3(Ss, NHh, Bb), 256, 0, stream>>>(qkv2, aout2);
            k_gemm<<<dim3((Dm + TS - 1) / TS, (Tt + TS - 1) / TS), blk, 0, stream>>>(
                aout2, o_w + (size_t)l * Dm * Dm, x2, x2, Tt, Dm, Dm);
            k_rmsnorm<<<Tt, 64, 0, stream>>>(x2, ln2_w + (size_t)l * Dm, h2);
            k_gateup<<<dim3((FFf + TS - 1) / TS, (Tt + TS - 1) / TS), blk, 0, stream>>>(
                h2, gate_w + (size_t)l * FFf * Dm, up_w + (size_t)l * FFf * Dm, act2, Tt, FFf, Dm);
            k_gemm<<<dim3((Dm + TS - 1) / TS, (Tt + TS - 1) / TS), blk, 0, stream>>>(
                act2, down_w + (size_t)l * Dm * FFf, x2, x2, Tt, Dm, FFf);
        }
        k_rmsnorm<<<Tt, 64, 0, stream>>>(x2, norm_w, h2);
        k_gemm<<<dim3((Vv + TS - 1) / TS, (Tt + TS - 1) / TS), blk, 0, stream>>>(
            h2, lm_w, nullptr, out, Tt, Vv, Dm);
    }
}